// Round 9
// baseline (685.364 us; speedup 1.0000x reference)
//
#include <hip/hip_runtime.h>
#include <math.h>
#include <stddef.h>

#define NB 16
#define ND 64
#define NN 4096
#define NCD 8
#define NITER 4
#define ATT_EPS 1e-8f
#define LNEPS 1e-5f
#define QSCALE 0.125f

typedef unsigned short u16;
typedef unsigned int u32;

// ---- workspace layout ----
static constexpr size_t EL_MAT   = (size_t)NB*NN*ND;           // elems per bf16 matrix
static constexpr size_t OFF_SCAL = 2*EL_MAT;                   // (floats) per-token 8 fp32 scalars
static constexpr size_t OFF_ACC  = OFF_SCAL + (size_t)NB*NN*8; // NB * 2 banks * 448
static constexpr size_t OFF_SFG  = OFF_ACC  + (size_t)NB*2*448;
static constexpr size_t OFF_SBG  = OFF_SFG  + (size_t)NB*256;
static constexpr size_t OFF_POS  = OFF_SBG  + (size_t)NB*64;
static constexpr size_t OFF_QW   = OFF_POS  + (size_t)NB*8;
static constexpr size_t OFF_QWBG = OFF_QW   + (size_t)NB*256;
static constexpr size_t OFF_QBBG = OFF_QWBG + (size_t)NB*64;
static constexpr size_t OFF_ABC  = OFF_QBBG + (size_t)NB;      // per (b,k): A,B,C,pad
static constexpr size_t OFF_GS   = OFF_ABC  + (size_t)NB*16;   // Gxx,Gyy,2*Gxy
static constexpr size_t OFF_CNT  = OFF_GS   + 4;               // 2 banks x NB u32 counters

#define A_S 0
#define A_W0 8
#define A_WX 12
#define A_WY 16
#define A_P 24
#define A_T 32
#define A_C 40
#define A_Y 80
#define A_YBG 336
#define ACC_STRIDE 448

// ---- helpers ----
__device__ __forceinline__ u16 f2bf(float f){
  u32 u = __float_as_uint(f);
  u32 r = (u + 0x7FFFu + ((u >> 16) & 1u)) >> 16;
  return (u16)r;
}
__device__ __forceinline__ float bf2f(u16 h){ return __uint_as_float(((u32)h) << 16); }

__device__ __forceinline__ float g16sum(float x){
  x += __shfl_xor(x, 1);
  x += __shfl_xor(x, 2);
  x += __shfl_xor(x, 4);
  x += __shfl_xor(x, 8);
  return x;
}
__device__ __forceinline__ float wavesum(float x){
  x += __shfl_xor(x, 1);  x += __shfl_xor(x, 2);
  x += __shfl_xor(x, 4);  x += __shfl_xor(x, 8);
  x += __shfl_xor(x, 16); x += __shfl_xor(x, 32);
  return x;
}
__device__ __forceinline__ float4 f4fma(float a, float4 w, float4 c){
  c.x = fmaf(a, w.x, c.x); c.y = fmaf(a, w.y, c.y);
  c.z = fmaf(a, w.z, c.z); c.w = fmaf(a, w.w, c.w);
  return c;
}
__device__ __forceinline__ float dot4(float4 a, float4 b){
  return fmaf(a.x,b.x, fmaf(a.y,b.y, fmaf(a.z,b.z, a.w*b.w)));
}
__device__ __forceinline__ float4 ln16v(float4 x, float4 g, float4 bb){
  float m = g16sum(x.x + x.y + x.z + x.w) * (1.0f/64.0f);
  float4 c = make_float4(x.x - m, x.y - m, x.z - m, x.w - m);
  float var = g16sum(c.x*c.x + c.y*c.y + c.z*c.z + c.w*c.w) * (1.0f/64.0f);
  float rs = rsqrtf(var + LNEPS);
  return make_float4(c.x*rs*g.x + bb.x, c.y*rs*g.y + bb.y,
                     c.z*rs*g.z + bb.z, c.w*rs*g.w + bb.w);
}
__device__ __forceinline__ float rowdot64f(const float* __restrict__ W, const float* x){
  const float4* w4 = (const float4*)W;
  const float4* x4 = (const float4*)x;
  float s0=0.f, s1=0.f, s2=0.f, s3=0.f;
  #pragma unroll
  for (int t = 0; t < 4; ++t){
    float4 w, xx;
    w = w4[t];     xx = x4[t];     s0 = fmaf(w.x,xx.x, fmaf(w.y,xx.y, fmaf(w.z,xx.z, fmaf(w.w,xx.w, s0))));
    w = w4[4+t];   xx = x4[4+t];   s1 = fmaf(w.x,xx.x, fmaf(w.y,xx.y, fmaf(w.z,xx.z, fmaf(w.w,xx.w, s1))));
    w = w4[8+t];   xx = x4[8+t];   s2 = fmaf(w.x,xx.x, fmaf(w.y,xx.y, fmaf(w.z,xx.z, fmaf(w.w,xx.w, s2))));
    w = w4[12+t];  xx = x4[12+t];  s3 = fmaf(w.x,xx.x, fmaf(w.y,xx.y, fmaf(w.z,xx.z, fmaf(w.w,xx.w, s3))));
  }
  return (s0+s1)+(s2+s3);
}
__device__ __forceinline__ float coldot64(const float* __restrict__ W, const float* x, int d){
  float s0=0.f, s1=0.f, s2=0.f, s3=0.f;
  #pragma unroll
  for (int t = 0; t < 16; ++t){
    s0 = fmaf(x[t],      W[(t)*64+d],      s0);
    s1 = fmaf(x[16+t],   W[(16+t)*64+d],   s1);
    s2 = fmaf(x[32+t],   W[(32+t)*64+d],   s2);
    s3 = fmaf(x[48+t],   W[(48+t)*64+d],   s3);
  }
  return (s0+s1)+(s2+s3);
}
#define XRED(x) do { x += __shfl_xor(x, 16); x += __shfl_xor(x, 32); } while (0)

// ---- k_pre: m-loop (35 KB LDS -> 4 blocks/CU), NO min-waves bound (r7 lesson:
// forcing 4 waves capped VGPR at 64 -> scratch spills -> 4.6x HBM, 90us) ----
__global__ __launch_bounds__(256) void k_pre(
    const float* __restrict__ feat,
    const float* __restrict__ w_kfg, const float* __restrict__ w_vfg,
    const float* __restrict__ w_kbg, const float* __restrict__ w_vbg,
    const float* __restrict__ w_grid, const float* __restrict__ b_grid,
    const float* __restrict__ ln_feat_g, const float* __restrict__ ln_feat_b,
    const float* __restrict__ ln_bg_g, const float* __restrict__ ln_bg_b,
    const float* __restrict__ ln_fg_g,
    float* __restrict__ ws)
{
  __shared__ __align__(16) float fl[64][68];   // LN'd feat tile
  __shared__ __align__(16) float wl[64][68];   // one weight matrix^T
  const int tid  = threadIdx.x;
  const int bid  = blockIdx.x;
  const int half = bid >> 10;        // 0 = fg pair, 1 = bg pair
  const int tb   = bid & 1023;       // token-block (64 tokens)
  const int i    = tid >> 4;
  const int j    = tid & 15;
  const int e0j  = 4*j;

  // stage feat tile with LN
  {
    const float4 lfg4 = *(const float4*)(ln_feat_g + e0j);
    const float4 lfb4 = *(const float4*)(ln_feat_b + e0j);
    #pragma unroll
    for (int it = 0; it < 4; ++it){
      const int tok = it*16 + i;
      const size_t gb = ((size_t)tb*64 + tok)*64 + e0j;
      const float4 f4 = *(const float4*)(feat + gb);
      *(float4*)&fl[tok][e0j] = ln16v(f4, lfg4, lfb4);
    }
  }

  const float4 bgr4 = *(const float4*)(b_grid + e0j);
  float4 wgx4, wgy4;
  {
    float4 w0 = *(const float4*)(w_grid + (e0j+0)*4);
    float4 w1 = *(const float4*)(w_grid + (e0j+1)*4);
    float4 w2 = *(const float4*)(w_grid + (e0j+2)*4);
    float4 w3 = *(const float4*)(w_grid + (e0j+3)*4);
    wgx4 = make_float4(w0.x-w0.z, w1.x-w1.z, w2.x-w2.z, w3.x-w3.z);
    wgy4 = make_float4(w0.y-w0.w, w1.y-w1.w, w2.y-w2.w, w3.y-w3.w);
  }
  float4 cx4 = make_float4(0,0,0,0), cy4 = cx4, lng4 = cx4;
  float4 lbg4 = cx4, lbb4 = cx4, ge[4];
  if (!half){
    lng4 = *(const float4*)(ln_fg_g + e0j);
    const float mx = g16sum(wgx4.x+wgx4.y+wgx4.z+wgx4.w)*(1.0f/64.0f);
    const float my = g16sum(wgy4.x+wgy4.y+wgy4.z+wgy4.w)*(1.0f/64.0f);
    cx4 = make_float4(wgx4.x-mx, wgx4.y-mx, wgx4.z-mx, wgx4.w-mx);
    cy4 = make_float4(wgy4.x-my, wgy4.y-my, wgy4.z-my, wgy4.w-my);
  } else {
    lbg4 = *(const float4*)(ln_bg_g + e0j);
    lbb4 = *(const float4*)(ln_bg_b + e0j);
    #pragma unroll
    for (int u = 0; u < 4; ++u){
      const size_t t = (size_t)tb*64 + u*16 + i;
      const int n = (int)(t & (NN-1));
      const float gx = -1.0f + (2.0f/63.0f)*(float)(n & 63);
      const float gy = -1.0f + (2.0f/63.0f)*(float)(n >> 6);
      ge[u] = make_float4(
          fmaf(gx, wgx4.x, fmaf(gy, wgy4.x, bgr4.x)),
          fmaf(gx, wgx4.y, fmaf(gy, wgy4.y, bgr4.y)),
          fmaf(gx, wgx4.z, fmaf(gy, wgy4.z, bgr4.z)),
          fmaf(gx, wgx4.w, fmaf(gy, wgy4.w, bgr4.w)));
    }
  }

  for (int m = 0; m < 2; ++m){
    const float* src = half ? (m ? w_vbg : w_kbg) : (m ? w_vfg : w_kfg);
    #pragma unroll
    for (int it = 0; it < 4; ++it){
      const int f = it*256 + tid;
      const int dd = f >> 4;
      const int s4 = f & 15;
      const float4 wv = *(const float4*)(src + dd*64 + 4*s4);
      wl[4*s4+0][dd] = wv.x;
      wl[4*s4+1][dd] = wv.y;
      wl[4*s4+2][dd] = wv.z;
      wl[4*s4+3][dd] = wv.w;
    }
    __syncthreads();

    float4 acc[4];
    #pragma unroll
    for (int u = 0; u < 4; ++u) acc[u] = make_float4(0,0,0,0);
    for (int e0 = 0; e0 < 64; e0 += 4){
      float4 a[4];
      #pragma unroll
      for (int u = 0; u < 4; ++u) a[u] = *(const float4*)&fl[u*16 + i][e0];
      #pragma unroll
      for (int l = 0; l < 4; ++l){
        const float4 bb = *(const float4*)&wl[e0+l][e0j];
        #pragma unroll
        for (int u = 0; u < 4; ++u){
          const float av = l==0 ? a[u].x : l==1 ? a[u].y : l==2 ? a[u].z : a[u].w;
          acc[u] = f4fma(av, bb, acc[u]);
        }
      }
    }

    if (!half){
      u16* dst = (u16*)ws + (m ? EL_MAT : 0);   // m0: uk, m1: cv0
      #pragma unroll
      for (int u = 0; u < 4; ++u){
        const size_t t = (size_t)tb*64 + u*16 + i;
        const size_t fb = t*64 + e0j;
        float4 kb = make_float4(acc[u].x+bgr4.x, acc[u].y+bgr4.y, acc[u].z+bgr4.z, acc[u].w+bgr4.w);
        float mk = g16sum(kb.x+kb.y+kb.z+kb.w)*(1.0f/64.0f);
        float4 c0 = make_float4(kb.x-mk, kb.y-mk, kb.z-mk, kb.w-mk);
        float s00 = g16sum(dot4(c0,c0));
        float s0x = g16sum(dot4(c0,cx4));
        float s0y = g16sum(dot4(c0,cy4));
        ushort4 pu;
        if (m == 0){
          pu.x = f2bf(c0.x*lng4.x); pu.y = f2bf(c0.y*lng4.y);
          pu.z = f2bf(c0.z*lng4.z); pu.w = f2bf(c0.w*lng4.w);
        } else {
          pu.x = f2bf(c0.x); pu.y = f2bf(c0.y); pu.z = f2bf(c0.z); pu.w = f2bf(c0.w);
        }
        *(ushort4*)(dst + fb) = pu;
        if (j == 0){
          *(float4*)(ws + OFF_SCAL + t*8 + 4*m) = make_float4(s00, 2.0f*s0x, 2.0f*s0y, 0.0f);
        }
      }
    } else {
      u16* dst = (u16*)ws + (m ? 3*EL_MAT : 2*EL_MAT);  // m0: xkbg, m1: xvbg
      #pragma unroll
      for (int u = 0; u < 4; ++u){
        const size_t t = (size_t)tb*64 + u*16 + i;
        const size_t fb = t*64 + e0j;
        float4 xk = make_float4(acc[u].x+ge[u].x, acc[u].y+ge[u].y, acc[u].z+ge[u].z, acc[u].w+ge[u].w);
        float4 nk = ln16v(xk, lbg4, lbb4);
        ushort4 p4; p4.x = f2bf(nk.x); p4.y = f2bf(nk.y); p4.z = f2bf(nk.z); p4.w = f2bf(nk.w);
        *(ushort4*)(dst + fb) = p4;
      }
    }
    __syncthreads();
  }
}

// ---- k_init0: slots + iter0 prep + zero acc banks + counters + GS ----
__global__ __launch_bounds__(64) void k_init0(
    const float* __restrict__ sfg0, const float* __restrict__ sbg0,
    const float* __restrict__ pos0, const float* __restrict__ w_grid,
    const float* __restrict__ ln_fg_g, const float* __restrict__ ln_fg_b,
    const float* __restrict__ ln_q_g, const float* __restrict__ ln_q_b,
    const float* __restrict__ w_q,
    const float* __restrict__ ln_qbg_g, const float* __restrict__ ln_qbg_b,
    const float* __restrict__ w_qbg,
    const float* __restrict__ w_mlp_fg, const float* __restrict__ b_mlp_fg,
    const float* __restrict__ w_mlp_bg, const float* __restrict__ b_mlp_bg,
    float* __restrict__ ws)
{
  const int k = blockIdx.x, b = blockIdx.y, d = threadIdx.x;
  __shared__ __align__(16) float xl[64], hl[64];
  const float wgx = w_grid[4*d] - w_grid[4*d+2];
  const float wgy = w_grid[4*d+1] - w_grid[4*d+3];
  const float mgx = wavesum(wgx)*(1.0f/64.0f);
  const float mgy = wavesum(wgy)*(1.0f/64.0f);
  const float cx = wgx - mgx, cy = wgy - mgy;

  if (k < 4){
    const float sv = sfg0[k*64 + d];
    ws[OFF_SFG + b*256 + k*64 + d] = sv;
    if (d < 2) ws[OFF_POS + b*8 + k*2 + d] = pos0[k*2 + d];
    const float cxg = cx*ln_fg_g[d];
    const float cyg = cy*ln_fg_g[d];
    const float m = wavesum(sv)*(1.0f/64.0f);
    const float c = sv - m;
    const float var = wavesum(c*c)*(1.0f/64.0f);
    const float rs = rsqrtf(var + LNEPS);
    xl[d] = c*rs*ln_q_g[d] + ln_q_b[d];
    __syncthreads();
    const float q = rowdot64f(w_q + d*64, xl);
    hl[d] = q;
    const float qb = wavesum(q * b_mlp_fg[d]);
    __syncthreads();
    const float qw = coldot64(w_mlp_fg, hl, d);
    ws[OFF_QW + b*256 + k*64 + d] = qw;
    const float A  = wavesum(qw * cxg);
    const float Bv = wavesum(qw * cyg);
    const float Cv = wavesum(qw * ln_fg_b[d]) + qb;
    if (d == 0){
      float* abc = ws + OFF_ABC + (size_t)(b*4 + k)*4;
      abc[0] = A; abc[1] = Bv; abc[2] = Cv;
    }
  } else {
    const float sv = sbg0[d];
    ws[OFF_SBG + b*64 + d] = sv;
    float* accb = ws + OFF_ACC + (size_t)b*2*ACC_STRIDE;
    for (int i2 = d; i2 < 2*ACC_STRIDE; i2 += 64) accb[i2] = 0.0f;
    if (d == 0){
      u32* cnt = (u32*)(ws + OFF_CNT);
      cnt[0*NB + b] = 0u;
      cnt[1*NB + b] = 0u;
    }
    if (b == 0){
      const float gxx = wavesum(cx*cx);
      const float gyy = wavesum(cy*cy);
      const float gxy = wavesum(cx*cy);
      if (d == 0){ ws[OFF_GS] = gxx; ws[OFF_GS+1] = gyy; ws[OFF_GS+2] = 2.0f*gxy; }
    }
    const float m = wavesum(sv)*(1.0f/64.0f);
    const float c = sv - m;
    const float var = wavesum(c*c)*(1.0f/64.0f);
    const float rs = rsqrtf(var + LNEPS);
    xl[d] = c*rs*ln_qbg_g[d] + ln_qbg_b[d];
    __syncthreads();
    const float q = rowdot64f(w_qbg + d*64, xl);
    hl[d] = q;
    const float qb = wavesum(q * b_mlp_bg[d]);
    __syncthreads();
    const float qw = coldot64(w_mlp_bg, hl, d);
    ws[OFF_QWBG + b*64 + d] = qw;
    if (d == 0) ws[OFF_QBBG + b] = qb;
  }
}

// ---- k_main: fused attention pass + last-block slot-update epilogue ----
// grid (64,16) x 256. Last block per b (device counter) runs the epilogue:
// waves 0-3 = fg slots 0-3 in parallel (wave-lockstep LDS, no __syncthreads in
// divergent region); wave 0 then bg slot; wave 1 zeroes next acc bank.
// gacc reads via atomicAdd(p,0) = coherent-point reads (XCD-safe).
template<int LAST>
__global__ __launch_bounds__(256) void k_main(
    const float* __restrict__ fc, const float* __restrict__ fcg,
    const float* __restrict__ fcb, const float* __restrict__ w_pos,
    const float* __restrict__ w_mlp_fg, const float* __restrict__ b_mlp_fg,
    const float* __restrict__ w_mlp_bg, const float* __restrict__ b_mlp_bg,
    const float* __restrict__ gfg_wih, const float* __restrict__ gfg_whh,
    const float* __restrict__ gfg_bih, const float* __restrict__ gfg_bhh,
    const float* __restrict__ gbg_wih, const float* __restrict__ gbg_whh,
    const float* __restrict__ gbg_bih, const float* __restrict__ gbg_bhh,
    const float* __restrict__ ln_rfg_g, const float* __restrict__ ln_rfg_b,
    const float* __restrict__ w_rfg, const float* __restrict__ b_rfg,
    const float* __restrict__ ln_rbg_g, const float* __restrict__ ln_rbg_b,
    const float* __restrict__ w_rbg, const float* __restrict__ b_rbg,
    const float* __restrict__ b_pos,
    const float* __restrict__ ln_fg_g, const float* __restrict__ ln_fg_b,
    const float* __restrict__ ln_q_g, const float* __restrict__ ln_q_b,
    const float* __restrict__ w_q,
    const float* __restrict__ ln_qbg_g, const float* __restrict__ ln_qbg_b,
    const float* __restrict__ w_qbg,
    const float* __restrict__ w_grid,
    float* __restrict__ ws, float* __restrict__ out, int bank)
{
  __shared__ float red[ACC_STRIDE];
  __shared__ __align__(16) float xs[5][64], hs[5][64], rs_[5][64];
  __shared__ u32 lastFlag;
  const int tid = threadIdx.x;
  const int b = blockIdx.y;
  for (int i2 = tid; i2 < ACC_STRIDE; i2 += 256) red[i2] = 0.0f;
  __syncthreads();

  const int G = tid >> 4;
  const int s = tid & 15;
  const int e0 = 4*s;

  float4 qw4[4]; float A[4], Bc[4], Cc[4], px[4], py[4];
  #pragma unroll
  for (int k = 0; k < 4; ++k){
    qw4[k] = *(const float4*)(ws + OFF_QW + (size_t)b*256 + k*64 + e0);
    const float* abc = ws + OFF_ABC + (size_t)(b*4 + k)*4;
    A[k] = abc[0]; Bc[k] = abc[1]; Cc[k] = abc[2];
    px[k] = ws[OFF_POS + b*8 + k*2 + 0];
    py[k] = ws[OFF_POS + b*8 + k*2 + 1];
  }
  const float4 qwbg4 = *(const float4*)(ws + OFF_QWBG + (size_t)b*64 + e0);
  const float qbbg = ws[OFF_QBBG + b];
  const float Gxx = ws[OFF_GS], Gyy = ws[OFF_GS+1], Gxy2 = ws[OFF_GS+2];

  const u16* ukh = (const u16*)ws;
  const u16* cvh = ukh + EL_MAT;
  const u16* xkh = cvh + EL_MAT;
  const u16* xvh = xkh + EL_MAT;

  float accY[4][4] = {};
  float accYbg[4] = {};
  float accS[5] = {};
  float accW0[4] = {}, accWx[4] = {}, accWy[4] = {};
  float accP[4][2] = {};
  float accT[4][2] = {};
  float accC[5] = {};

  const int nbase = blockIdx.x*64 + G*4;
  for (int i = 0; i < 4; ++i){
    const int n = nbase + i;
    const size_t tok = ((size_t)b << 12) + (size_t)n;
    const size_t rbase = tok*64 + e0;
    const ushort4 r0 = *(const ushort4*)(ukh + rbase);
    const ushort4 r1 = *(const ushort4*)(cvh + rbase);
    const ushort4 r2 = *(const ushort4*)(xkh + rbase);
    const ushort4 r3 = *(const ushort4*)(xvh + rbase);
    const float4 sA = *(const float4*)(ws + OFF_SCAL + tok*8);
    const float4 sB = *(const float4*)(ws + OFF_SCAL + tok*8 + 4);
    const float4 uk4  = make_float4(bf2f(r0.x), bf2f(r0.y), bf2f(r0.z), bf2f(r0.w));
    const float4 cv4  = make_float4(bf2f(r1.x), bf2f(r1.y), bf2f(r1.z), bf2f(r1.w));
    const float4 xkb4 = make_float4(bf2f(r2.x), bf2f(r2.y), bf2f(r2.z), bf2f(r2.w));
    const float4 xvb4 = make_float4(bf2f(r3.x), bf2f(r3.y), bf2f(r3.z), bf2f(r3.w));
    const float gx = -1.0f + (2.0f/63.0f)*(float)(n & 63);
    const float gy = -1.0f + (2.0f/63.0f)*(float)(n >> 6);
    float fcv = 0.0f, wpx = 0.0f, wpy = 0.0f;
    if (LAST){
      float v = (s < 8) ? fc[tok*8 + s] : 0.0f;
      float m8 = v;
      m8 += __shfl_xor(m8, 1); m8 += __shfl_xor(m8, 2); m8 += __shfl_xor(m8, 4);
      m8 *= 0.125f;
      const float cc = v - m8;
      float va = cc*cc;
      va += __shfl_xor(va, 1); va += __shfl_xor(va, 2); va += __shfl_xor(va, 4);
      va *= 0.125f;
      const float rs8 = rsqrtf(va + LNEPS);
      fcv = (s < 8) ? cc*rs8*fcg[s] + fcb[s] : 0.0f;
    } else {
      wpx = w_pos[n]; wpy = w_pos[NN + n];
    }

    float a0 = g16sum(dot4(xkb4, qwbg4));
    a0 = QSCALE*(a0 + qbbg);

    float a[4], rsv[4];
    #pragma unroll
    for (int k = 0; k < 4; ++k){
      const float rx = gx - px[k];
      const float ry = gy - py[k];
      const float rxy = rx*ry;
      float h1 = fmaf(rx, Gxx, sA.y);
      float h2 = fmaf(ry, Gyy, sA.z);
      float vk = fmaf(rx, h1, fmaf(ry, h2, sA.x));
      vk = fmaf(rxy, Gxy2, vk);
      const float rsk = rsqrtf(fmaf(vk, 1.0f/64.0f, LNEPS));
      float h1v = fmaf(rx, Gxx, sB.y);
      float h2v = fmaf(ry, Gyy, sB.z);
      float vv = fmaf(rx, h1v, fmaf(ry, h2v, sB.x));
      vv = fmaf(rxy, Gxy2, vv);
      rsv[k] = rsqrtf(fmaf(vv, 1.0f/64.0f, LNEPS));
      float dk = g16sum(dot4(uk4, qw4[k]));
      dk = fmaf(rx, A[k], dk);
      dk = fmaf(ry, Bc[k], dk);
      a[k] = QSCALE * fmaf(rsk, dk, Cc[k]);
    }
    const float mx = fmaxf(fmaxf(fmaxf(a[0],a[1]), fmaxf(a[2],a[3])), a0);
    float p0 = __expf(a0 - mx);
    float pk[4];
    float sum = p0;
    #pragma unroll
    for (int k = 0; k < 4; ++k){ pk[k] = __expf(a[k]-mx); sum += pk[k]; }
    const float inv = 1.0f/sum;
    p0 = fmaf(p0, inv, ATT_EPS);
    #pragma unroll
    for (int k = 0; k < 4; ++k) pk[k] = fmaf(pk[k], inv, ATT_EPS);

    accS[0] += p0;
    accYbg[0] = fmaf(p0, xvb4.x, accYbg[0]);
    accYbg[1] = fmaf(p0, xvb4.y, accYbg[1]);
    accYbg[2] = fmaf(p0, xvb4.z, accYbg[2]);
    accYbg[3] = fmaf(p0, xvb4.w, accYbg[3]);
    if (LAST) accC[0] = fmaf(p0, fcv, accC[0]);
    #pragma unroll
    for (int k = 0; k < 4; ++k){
      accS[k+1] += pk[k];
      const float prv = pk[k]*rsv[k];
      accY[k][0] = fmaf(prv, cv4.x, accY[k][0]);
      accY[k][1] = fmaf(prv, cv4.y, accY[k][1]);
      accY[k][2] = fmaf(prv, cv4.z, accY[k][2]);
      accY[k][3] = fmaf(prv, cv4.w, accY[k][3]);
      accW0[k] += prv;
      accWx[k] = fmaf(prv, gx, accWx[k]);
      accWy[k] = fmaf(prv, gy, accWy[k]);
      if (LAST){
        accC[k+1] = fmaf(pk[k], fcv, accC[k+1]);
      } else {
        accP[k][0] = fmaf(pk[k], gx, accP[k][0]);
        accP[k][1] = fmaf(pk[k], gy, accP[k][1]);
        accT[k][0] = fmaf(pk[k], wpx, accT[k][0]);
        accT[k][1] = fmaf(pk[k], wpy, accT[k][1]);
      }
    }
  }

  #pragma unroll
  for (int k = 0; k < 4; ++k){
    #pragma unroll
    for (int j2 = 0; j2 < 4; ++j2){ float x = accY[k][j2]; XRED(x); accY[k][j2] = x; }
    float x;
    x = accW0[k]; XRED(x); accW0[k] = x;
    x = accWx[k]; XRED(x); accWx[k] = x;
    x = accWy[k]; XRED(x); accWy[k] = x;
    x = accP[k][0]; XRED(x); accP[k][0] = x;
    x = accP[k][1]; XRED(x); accP[k][1] = x;
    x = accT[k][0]; XRED(x); accT[k][0] = x;
    x = accT[k][1]; XRED(x); accT[k][1] = x;
  }
  #pragma unroll
  for (int j2 = 0; j2 < 4; ++j2){ float x = accYbg[j2]; XRED(x); accYbg[j2] = x; }
  #pragma unroll
  for (int sl = 0; sl < 5; ++sl){ float x = accS[sl]; XRED(x); accS[sl] = x; }
  #pragma unroll
  for (int sl = 0; sl < 5; ++sl){ float x = accC[sl]; XRED(x); accC[sl] = x; }

  const bool g0 = (G & 3) == 0;
  if (g0){
    #pragma unroll
    for (int k = 0; k < 4; ++k){
      atomicAdd(&red[A_Y + k*64 + e0 + 0], accY[k][0]);
      atomicAdd(&red[A_Y + k*64 + e0 + 1], accY[k][1]);
      atomicAdd(&red[A_Y + k*64 + e0 + 2], accY[k][2]);
      atomicAdd(&red[A_Y + k*64 + e0 + 3], accY[k][3]);
    }
    atomicAdd(&red[A_YBG + e0 + 0], accYbg[0]);
    atomicAdd(&red[A_YBG + e0 + 1], accYbg[1]);
    atomicAdd(&red[A_YBG + e0 + 2], accYbg[2]);
    atomicAdd(&red[A_YBG + e0 + 3], accYbg[3]);
    if (s == 0){
      #pragma unroll
      for (int sl = 0; sl < 5; ++sl) atomicAdd(&red[A_S + sl], accS[sl]);
      #pragma unroll
      for (int k = 0; k < 4; ++k){
        atomicAdd(&red[A_W0 + k], accW0[k]);
        atomicAdd(&red[A_WX + k], accWx[k]);
        atomicAdd(&red[A_WY + k], accWy[k]);
      }
      if (!LAST){
        #pragma unroll
        for (int k = 0; k < 4; ++k){
          atomicAdd(&red[A_P + k*2 + 0], accP[k][0]);
          atomicAdd(&red[A_P + k*2 + 1], accP[k][1]);
          atomicAdd(&red[A_T + k*2 + 0], accT[k][0]);
          atomicAdd(&red[A_T + k*2 + 1], accT[k][1]);
        }
      }
    }
    if (LAST && s < 8){
      #pragma unroll
      for (int sl = 0; sl < 5; ++sl) atomicAdd(&red[A_C + sl*8 + s], accC[sl]);
    }
  }
  __syncthreads();
  float* accR = ws + OFF_ACC + ((size_t)b*2 + bank)*ACC_STRIDE;
  for (int i2 = tid; i2 < ACC_STRIDE; i2 += 256){
    const float v = red[i2];
    if (v != 0.0f) atomicAdd(&accR[i2], v);
  }

  // ---- last-block epilogue ----
  __threadfence();
  if (tid == 0){
    u32* cnt = (u32*)(ws + OFF_CNT) + bank*NB + b;
    const u32 old = atomicAdd(cnt, 1u);
    lastFlag = (old == 63u) ? 1u : 0u;
    if (old == 63u) *cnt = 0u;   // reset for reuse (bank reused at it+2 / next replay)
  }
  __syncthreads();
  if (lastFlag == 0u) return;

  float* accZ = ws + OFF_ACC + ((size_t)b*2 + (bank^1))*ACC_STRIDE;
  const int w = tid >> 6;   // wave id = slot (0..3 fg)
  const int d = tid & 63;

  // coherent-point reads of the accumulator
  #define ARD(p) atomicAdd((p), 0.0f)

  // grid-direction constants (per-lane d)
  const float wgx = w_grid[4*d] - w_grid[4*d+2];
  const float wgy = w_grid[4*d+1] - w_grid[4*d+3];
  const float mgx = wavesum(wgx)*(1.0f/64.0f);
  const float mgy = wavesum(wgy)*(1.0f/64.0f);
  const float cxg = (wgx - mgx)*ln_fg_g[d];
  const float cyg = (wgy - mgy)*ln_fg_g[d];

  // ---- fg slot w (all 4 waves in parallel; wave-lockstep LDS, no barriers) ----
  {
    const float S = ARD(&accR[A_S + 1 + w]);
    const float invS = 1.0f/S;
    const float pxv = ws[OFF_POS + b*8 + w*2 + 0];
    const float pyv = ws[OFF_POS + b*8 + w*2 + 1];
    const float W0 = ARD(&accR[A_W0 + w]);
    const float WX = ARD(&accR[A_WX + w]);
    const float WY = ARD(&accR[A_WY + w]);
    const float wxc = (WX - pxv*W0)*invS;
    const float wyc = (WY - pyv*W0)*invS;
    const float Yd = ARD(&accR[A_Y + w*64 + d]);
    xs[w][d] = Yd*invS*ln_fg_g[d] + wxc*cxg + wyc*cyg + ln_fg_b[d];
    if (LAST){
      const float o = b_mlp_fg[d] + rowdot64f(w_mlp_fg + d*64, xs[w]);
      out[(size_t)(b*5 + 1 + w)*72 + d] = o;
      if (d < 8) out[(size_t)(b*5 + 1 + w)*72 + 64 + d] = ARD(&accR[A_C + (w+1)*8 + d])*invS;
    } else {
      const float h = ws[OFF_SFG + b*256 + w*64 + d];
      hs[w][d] = h;
      const float upd = b_mlp_fg[d] + rowdot64f(w_mlp_fg + d*64, xs[w]);
      xs[w][d] = upd;
      const float gir = gfg_bih[d]     + rowdot64f(gfg_wih + d*64, xs[w]);
      const float giz = gfg_bih[64+d]  + rowdot64f(gfg_wih + (64+d)*64, xs[w]);
      const float gin = gfg_bih[128+d] + rowdot64f(gfg_wih + (128+d)*64, xs[w]);
      const float ghr = gfg_bhh[d]     + rowdot64f(gfg_whh + d*64, hs[w]);
      const float ghz = gfg_bhh[64+d]  + rowdot64f(gfg_whh + (64+d)*64, hs[w]);
      const float ghn = gfg_bhh[128+d] + rowdot64f(gfg_whh + (128+d)*64, hs[w]);
      const float r = 1.0f/(1.0f + expf(-(gir+ghr)));
      const float z = 1.0f/(1.0f + expf(-(giz+ghz)));
      const float nng = tanhf(fmaf(r, ghn, gin));
      const float hnew = (1.0f - z)*nng + z*h;
      const float m = wavesum(hnew)*(1.0f/64.0f);
      const float c = hnew - m;
      const float var = wavesum(c*c)*(1.0f/64.0f);
      const float rs = rsqrtf(var + LNEPS);
      rs_[w][d] = c*rs*ln_rfg_g[d] + ln_rfg_b[d];
      const float snew = hnew + b_rfg[d] + rowdot64f(w_rfg + d*64, rs_[w]);
      ws[OFF_SFG + b*256 + w*64 + d] = snew;
      if (d < 2){
        const float P = ARD(&accR[A_P + w*2 + d])*invS;
        const float T = ARD(&accR[A_T + w*2 + d])*invS;
        float pn = P + tanhf(T + b_pos[d])*0.2f;
        pn = fminf(1.0f, fmaxf(-1.0f, pn));
        ws[OFF_POS + b*8 + w*2 + d] = pn;
      }
      // prep next iter
      const float m2 = wavesum(snew)*(1.0f/64.0f);
      const float c2 = snew - m2;
      const float var2 = wavesum(c2*c2)*(1.0f/64.0f);
      const float rs2 = rsqrtf(var2 + LNEPS);
      xs[w][d] = c2*rs2*ln_q_g[d] + ln_q_b[d];
      const float q = rowdot64f(w_q + d*64, xs[w]);
      hs[w][d] = q;
      const float qb = wavesum(q * b_mlp_fg[d]);
      const float qw = coldot64(w_mlp_fg, hs[w], d);
      ws[OFF_QW + b*256 + w*64 + d] = qw;
      const float Af  = wavesum(qw * cxg);
      const float Bf  = wavesum(qw * cyg);
      const float Cf  = wavesum(qw * ln_fg_b[d]) + qb;
      if (d == 0){
        float* abc = ws + OFF_ABC + (size_t)(b*4 + w)*4;
        abc[0] = Af; abc[1] = Bf; abc[2] = Cf;
      }
    }
  }

  // ---- wave 1: zero the other bank for the next dispatch ----
  if (w == 1 && !LAST){
    for (int i2 = d; i2 < ACC_STRIDE; i2 += 64) accZ[i2] = 0.0f;
  }

  // ---- wave 0: bg slot ----
  if (w == 0){
    const float S0 = ARD(&accR[A_S]);
    const float invS = 1.0f/S0;
    xs[4][d] = ARD(&accR[A_YBG + d])*invS;
    if (LAST){
      const float o = b_mlp_bg[d] + rowdot64f(w_mlp_bg + d*64, xs[4]);
      out[(size_t)(b*5)*72 + d] = o;
      if (d < 8) out[(size_t)(b*5)*72 + 64 + d] = ARD(&accR[A_C + d])*invS;
    } else {
      const float h = ws[OFF_SBG + b*64 + d];
      hs[4][d] = h;
      const float upd = b_mlp_bg[d] + rowdot64f(w_mlp_bg + d*64, xs[4]);
      xs[4][d] = upd;
      const float gir = gbg_bih[d]     + rowdot64f(gbg_wih + d*64, xs[4]);
      const float giz = gbg_bih[64+d]  + rowdot64f(gbg_wih + (64+d)*64, xs[4]);
      const float gin = gbg_bih[128+d] + rowdot64f(gbg_wih + (128+d)*64, xs[4]);
      const float ghr = gbg_bhh[d]     + rowdot64f(gbg_whh + d*64, hs[4]);
      const float ghz = gbg_bhh[64+d]  + rowdot64f(gbg_whh + (64+d)*64, hs[4]);
      const float ghn = gbg_bhh[128+d] + rowdot64f(gbg_whh + (128+d)*64, hs[4]);
      const float r = 1.0f/(1.0f + expf(-(gir+ghr)));
      const float z = 1.0f/(1.0f + expf(-(giz+ghz)));
      const float nng = tanhf(fmaf(r, ghn, gin));
      const float hnew = (1.0f - z)*nng + z*h;
      const float m = wavesum(hnew)*(1.0f/64.0f);
      const float c = hnew - m;
      const float var = wavesum(c*c)*(1.0f/64.0f);
      const float rs = rsqrtf(var + LNEPS);
      rs_[4][d] = c*rs*ln_rbg_g[d] + ln_rbg_b[d];
      const float snew = hnew + b_rbg[d] + rowdot64f(w_rbg + d*64, rs_[4]);
      ws[OFF_SBG + b*64 + d] = snew;
      const float m2 = wavesum(snew)*(1.0f/64.0f);
      const float c2 = snew - m2;
      const float var2 = wavesum(c2*c2)*(1.0f/64.0f);
      const float rs2 = rsqrtf(var2 + LNEPS);
      xs[4][d] = c2*rs2*ln_qbg_g[d] + ln_qbg_b[d];
      const float q = rowdot64f(w_qbg + d*64, xs[4]);
      hs[4][d] = q;
      const float qb = wavesum(q * b_mlp_bg[d]);
      const float qw = coldot64(w_mlp_bg, hs[4], d);
      ws[OFF_QWBG + b*64 + d] = qw;
      if (d == 0) ws[OFF_QBBG + b] = qb;
    }
  }
  #undef ARD
}

extern "C" void kernel_launch(void* const* d_in, const int* in_sizes, int n_in,
                              void* d_out, int out_size, void* d_ws, size_t ws_size,
                              hipStream_t stream)
{
  const float* feat          = (const float*)d_in[0];
  const float* feat_color    = (const float*)d_in[1];
  const float* w_grid        = (const float*)d_in[2];
  const float* b_grid        = (const float*)d_in[3];
  const float* w_kfg         = (const float*)d_in[4];
  const float* w_vfg         = (const float*)d_in[5];
  const float* w_kbg         = (const float*)d_in[6];
  const float* w_vbg         = (const float*)d_in[7];
  const float* ln_fg_g       = (const float*)d_in[8];
  const float* ln_fg_b       = (const float*)d_in[9];
  const float* w_mlp_fg      = (const float*)d_in[10];
  const float* b_mlp_fg      = (const float*)d_in[11];
  const float* ln_bg_g       = (const float*)d_in[12];
  const float* ln_bg_b       = (const float*)d_in[13];
  const float* w_mlp_bg      = (const float*)d_in[14];
  const float* b_mlp_bg      = (const float*)d_in[15];
  const float* slots_init_fg = (const float*)d_in[16];
  const float* slots_init_bg = (const float*)d_in[17];
  const float* fg_position   = (const float*)d_in[18];
  const float* w_pos         = (const float*)d_in[19];
  const float* b_pos         = (const float*)d_in[20];
  const float* ln_q_g        = (const float*)d_in[21];
  const float* ln_q_b        = (const float*)d_in[22];
  const float* w_q           = (const float*)d_in[23];
  const float* ln_qbg_g      = (const float*)d_in[24];
  const float* ln_qbg_b      = (const float*)d_in[25];
  const float* w_qbg         = (const float*)d_in[26];
  const float* gfg_wih       = (const float*)d_in[27];
  const float* gfg_whh       = (const float*)d_in[28];
  const float* gfg_bih       = (const float*)d_in[29];
  const float* gfg_bhh       = (const float*)d_in[30];
  const float* gbg_wih       = (const float*)d_in[31];
  const float* gbg_whh       = (const float*)d_in[32];
  const float* gbg_bih       = (const float*)d_in[33];
  const float* gbg_bhh       = (const float*)d_in[34];
  const float* ln_rfg_g      = (const float*)d_in[35];
  const float* ln_rfg_b      = (const float*)d_in[36];
  const float* w_rfg         = (const float*)d_in[37];
  const float* b_rfg         = (const float*)d_in[38];
  const float* ln_rbg_g      = (const float*)d_in[39];
  const float* ln_rbg_b      = (const float*)d_in[40];
  const float* w_rbg         = (const float*)d_in[41];
  const float* b_rbg         = (const float*)d_in[42];
  const float* ln_feat_g     = (const float*)d_in[43];
  const float* ln_feat_b     = (const float*)d_in[44];
  const float* ln_fc_g       = (const float*)d_in[45];
  const float* ln_fc_b       = (const float*)d_in[46];
  float* ws  = (float*)d_ws;
  float* out = (float*)d_out;

  hipLaunchKernelGGL(k_init0, dim3(5,16), dim3(64), 0, stream,
                     slots_init_fg, slots_init_bg, fg_position, w_grid,
                     ln_fg_g, ln_fg_b, ln_q_g, ln_q_b, w_q,
                     ln_qbg_g, ln_qbg_b, w_qbg,
                     w_mlp_fg, b_mlp_fg, w_mlp_bg, b_mlp_bg, ws);
  hipLaunchKernelGGL(k_pre, dim3(2048), dim3(256), 0, stream,
                     feat, w_kfg, w_vfg, w_kbg, w_vbg, w_grid, b_grid,
                     ln_feat_g, ln_feat_b, ln_bg_g, ln_bg_b, ln_fg_g, ws);
  for (int it = 0; it < NITER; ++it){
    const int bank = it & 1;
    if (it < NITER-1){
      hipLaunchKernelGGL((k_main<0>), dim3(64,16), dim3(256), 0, stream,
                         feat_color, ln_fc_g, ln_fc_b, w_pos,
                         w_mlp_fg, b_mlp_fg, w_mlp_bg, b_mlp_bg,
                         gfg_wih, gfg_whh, gfg_bih, gfg_bhh,
                         gbg_wih, gbg_whh, gbg_bih, gbg_bhh,
                         ln_rfg_g, ln_rfg_b, w_rfg, b_rfg,
                         ln_rbg_g, ln_rbg_b, w_rbg, b_rbg,
                         b_pos, ln_fg_g, ln_fg_b,
                         ln_q_g, ln_q_b, w_q, ln_qbg_g, ln_qbg_b, w_qbg,
                         w_grid, ws, out, bank);
    } else {
      hipLaunchKernelGGL((k_main<1>), dim3(64,16), dim3(256), 0, stream,
                         feat_color, ln_fc_g, ln_fc_b, w_pos,
                         w_mlp_fg, b_mlp_fg, w_mlp_bg, b_mlp_bg,
                         gfg_wih, gfg_whh, gfg_bih, gfg_bhh,
                         gbg_wih, gbg_whh, gbg_bih, gbg_bhh,
                         ln_rfg_g, ln_rfg_b, w_rfg, b_rfg,
                         ln_rbg_g, ln_rbg_b, w_rbg, b_rbg,
                         b_pos, ln_fg_g, ln_fg_b,
                         ln_q_g, ln_q_b, w_q, ln_qbg_g, ln_qbg_b, w_qbg,
                         w_grid, ws, out, bank);
    }
  }
}

// Round 10
// 198.606 us; speedup vs baseline: 3.4509x; 3.4509x over previous
//
#include <hip/hip_runtime.h>
#include <math.h>
#include <stddef.h>

#define NB 16
#define ND 64
#define NN 4096
#define NCD 8
#define NITER 4
#define ATT_EPS 1e-8f
#define LNEPS 1e-5f
#define QSCALE 0.125f

typedef unsigned short u16;
typedef unsigned int u32;

// ---- workspace layout ----
static constexpr size_t EL_MAT   = (size_t)NB*NN*ND;           // elems per bf16 matrix
static constexpr size_t OFF_SCAL = 2*EL_MAT;                   // (floats) per-token 8 fp32 scalars
static constexpr size_t OFF_ACC  = OFF_SCAL + (size_t)NB*NN*8; // NB * 2 banks * 448
static constexpr size_t OFF_SFG  = OFF_ACC  + (size_t)NB*2*448;
static constexpr size_t OFF_SBG  = OFF_SFG  + (size_t)NB*256;
static constexpr size_t OFF_POS  = OFF_SBG  + (size_t)NB*64;
static constexpr size_t OFF_QW   = OFF_POS  + (size_t)NB*8;
static constexpr size_t OFF_QWBG = OFF_QW   + (size_t)NB*256;
static constexpr size_t OFF_QBBG = OFF_QWBG + (size_t)NB*64;
static constexpr size_t OFF_ABC  = OFF_QBBG + (size_t)NB;      // per (b,k): A,B,C,pad
static constexpr size_t OFF_GS   = OFF_ABC  + (size_t)NB*16;   // Gxx,Gyy,2*Gxy

#define A_S 0
#define A_W0 8
#define A_WX 12
#define A_WY 16
#define A_P 24
#define A_T 32
#define A_C 40
#define A_Y 80
#define A_YBG 336
#define ACC_STRIDE 448

// ---- helpers ----
__device__ __forceinline__ u16 f2bf(float f){
  u32 u = __float_as_uint(f);
  u32 r = (u + 0x7FFFu + ((u >> 16) & 1u)) >> 16;
  return (u16)r;
}
__device__ __forceinline__ float bf2f(u16 h){ return __uint_as_float(((u32)h) << 16); }

__device__ __forceinline__ float g16sum(float x){
  x += __shfl_xor(x, 1);
  x += __shfl_xor(x, 2);
  x += __shfl_xor(x, 4);
  x += __shfl_xor(x, 8);
  return x;
}
__device__ __forceinline__ float wavesum(float x){
  x += __shfl_xor(x, 1);  x += __shfl_xor(x, 2);
  x += __shfl_xor(x, 4);  x += __shfl_xor(x, 8);
  x += __shfl_xor(x, 16); x += __shfl_xor(x, 32);
  return x;
}
__device__ __forceinline__ float4 f4fma(float a, float4 w, float4 c){
  c.x = fmaf(a, w.x, c.x); c.y = fmaf(a, w.y, c.y);
  c.z = fmaf(a, w.z, c.z); c.w = fmaf(a, w.w, c.w);
  return c;
}
__device__ __forceinline__ float dot4(float4 a, float4 b){
  return fmaf(a.x,b.x, fmaf(a.y,b.y, fmaf(a.z,b.z, a.w*b.w)));
}
__device__ __forceinline__ float4 ln16v(float4 x, float4 g, float4 bb){
  float m = g16sum(x.x + x.y + x.z + x.w) * (1.0f/64.0f);
  float4 c = make_float4(x.x - m, x.y - m, x.z - m, x.w - m);
  float var = g16sum(c.x*c.x + c.y*c.y + c.z*c.z + c.w*c.w) * (1.0f/64.0f);
  float rs = rsqrtf(var + LNEPS);
  return make_float4(c.x*rs*g.x + bb.x, c.y*rs*g.y + bb.y,
                     c.z*rs*g.z + bb.z, c.w*rs*g.w + bb.w);
}
__device__ __forceinline__ float rowdot64f(const float* __restrict__ W, const float* x){
  const float4* w4 = (const float4*)W;
  const float4* x4 = (const float4*)x;
  float s0=0.f, s1=0.f, s2=0.f, s3=0.f;
  #pragma unroll
  for (int t = 0; t < 4; ++t){
    float4 w, xx;
    w = w4[t];     xx = x4[t];     s0 = fmaf(w.x,xx.x, fmaf(w.y,xx.y, fmaf(w.z,xx.z, fmaf(w.w,xx.w, s0))));
    w = w4[4+t];   xx = x4[4+t];   s1 = fmaf(w.x,xx.x, fmaf(w.y,xx.y, fmaf(w.z,xx.z, fmaf(w.w,xx.w, s1))));
    w = w4[8+t];   xx = x4[8+t];   s2 = fmaf(w.x,xx.x, fmaf(w.y,xx.y, fmaf(w.z,xx.z, fmaf(w.w,xx.w, s2))));
    w = w4[12+t];  xx = x4[12+t];  s3 = fmaf(w.x,xx.x, fmaf(w.y,xx.y, fmaf(w.z,xx.z, fmaf(w.w,xx.w, s3))));
  }
  return (s0+s1)+(s2+s3);
}
__device__ __forceinline__ float coldot64(const float* __restrict__ W, const float* x, int d){
  float s0=0.f, s1=0.f, s2=0.f, s3=0.f;
  #pragma unroll
  for (int t = 0; t < 16; ++t){
    s0 = fmaf(x[t],      W[(t)*64+d],      s0);
    s1 = fmaf(x[16+t],   W[(16+t)*64+d],   s1);
    s2 = fmaf(x[32+t],   W[(32+t)*64+d],   s2);
    s3 = fmaf(x[48+t],   W[(48+t)*64+d],   s3);
  }
  return (s0+s1)+(s2+s3);
}
#define XRED(x) do { x += __shfl_xor(x, 16); x += __shfl_xor(x, 32); } while (0)

// ---- k_pre: m-loop (34.8 KB LDS -> 4 blocks/CU), NATURAL VGPR (r7 lesson:
// forcing min-waves=4 capped VGPR at 64 -> scratch spills -> 4.6x HBM, 90us;
// r9 showed this m-loop shape compiles cleanly without the cap) ----
__global__ __launch_bounds__(256) void k_pre(
    const float* __restrict__ feat,
    const float* __restrict__ w_kfg, const float* __restrict__ w_vfg,
    const float* __restrict__ w_kbg, const float* __restrict__ w_vbg,
    const float* __restrict__ w_grid, const float* __restrict__ b_grid,
    const float* __restrict__ ln_feat_g, const float* __restrict__ ln_feat_b,
    const float* __restrict__ ln_bg_g, const float* __restrict__ ln_bg_b,
    const float* __restrict__ ln_fg_g,
    float* __restrict__ ws)
{
  __shared__ __align__(16) float fl[64][68];   // LN'd feat tile
  __shared__ __align__(16) float wl[64][68];   // one weight matrix^T
  const int tid  = threadIdx.x;
  const int bid  = blockIdx.x;
  const int half = bid >> 10;        // 0 = fg pair, 1 = bg pair
  const int tb   = bid & 1023;       // token-block (64 tokens)
  const int i    = tid >> 4;
  const int j    = tid & 15;
  const int e0j  = 4*j;

  // stage feat tile with LN
  {
    const float4 lfg4 = *(const float4*)(ln_feat_g + e0j);
    const float4 lfb4 = *(const float4*)(ln_feat_b + e0j);
    #pragma unroll
    for (int it = 0; it < 4; ++it){
      const int tok = it*16 + i;
      const size_t gb = ((size_t)tb*64 + tok)*64 + e0j;
      const float4 f4 = *(const float4*)(feat + gb);
      *(float4*)&fl[tok][e0j] = ln16v(f4, lfg4, lfb4);
    }
  }

  const float4 bgr4 = *(const float4*)(b_grid + e0j);
  float4 wgx4, wgy4;
  {
    float4 w0 = *(const float4*)(w_grid + (e0j+0)*4);
    float4 w1 = *(const float4*)(w_grid + (e0j+1)*4);
    float4 w2 = *(const float4*)(w_grid + (e0j+2)*4);
    float4 w3 = *(const float4*)(w_grid + (e0j+3)*4);
    wgx4 = make_float4(w0.x-w0.z, w1.x-w1.z, w2.x-w2.z, w3.x-w3.z);
    wgy4 = make_float4(w0.y-w0.w, w1.y-w1.w, w2.y-w2.w, w3.y-w3.w);
  }
  float4 cx4 = make_float4(0,0,0,0), cy4 = cx4, lng4 = cx4;
  float4 lbg4 = cx4, lbb4 = cx4, ge[4];
  if (!half){
    lng4 = *(const float4*)(ln_fg_g + e0j);
    const float mx = g16sum(wgx4.x+wgx4.y+wgx4.z+wgx4.w)*(1.0f/64.0f);
    const float my = g16sum(wgy4.x+wgy4.y+wgy4.z+wgy4.w)*(1.0f/64.0f);
    cx4 = make_float4(wgx4.x-mx, wgx4.y-mx, wgx4.z-mx, wgx4.w-mx);
    cy4 = make_float4(wgy4.x-my, wgy4.y-my, wgy4.z-my, wgy4.w-my);
  } else {
    lbg4 = *(const float4*)(ln_bg_g + e0j);
    lbb4 = *(const float4*)(ln_bg_b + e0j);
    #pragma unroll
    for (int u = 0; u < 4; ++u){
      const size_t t = (size_t)tb*64 + u*16 + i;
      const int n = (int)(t & (NN-1));
      const float gx = -1.0f + (2.0f/63.0f)*(float)(n & 63);
      const float gy = -1.0f + (2.0f/63.0f)*(float)(n >> 6);
      ge[u] = make_float4(
          fmaf(gx, wgx4.x, fmaf(gy, wgy4.x, bgr4.x)),
          fmaf(gx, wgx4.y, fmaf(gy, wgy4.y, bgr4.y)),
          fmaf(gx, wgx4.z, fmaf(gy, wgy4.z, bgr4.z)),
          fmaf(gx, wgx4.w, fmaf(gy, wgy4.w, bgr4.w)));
    }
  }

  for (int m = 0; m < 2; ++m){
    const float* src = half ? (m ? w_vbg : w_kbg) : (m ? w_vfg : w_kfg);
    #pragma unroll
    for (int it = 0; it < 4; ++it){
      const int f = it*256 + tid;
      const int dd = f >> 4;
      const int s4 = f & 15;
      const float4 wv = *(const float4*)(src + dd*64 + 4*s4);
      wl[4*s4+0][dd] = wv.x;
      wl[4*s4+1][dd] = wv.y;
      wl[4*s4+2][dd] = wv.z;
      wl[4*s4+3][dd] = wv.w;
    }
    __syncthreads();

    float4 acc[4];
    #pragma unroll
    for (int u = 0; u < 4; ++u) acc[u] = make_float4(0,0,0,0);
    for (int e0 = 0; e0 < 64; e0 += 4){
      float4 a[4];
      #pragma unroll
      for (int u = 0; u < 4; ++u) a[u] = *(const float4*)&fl[u*16 + i][e0];
      #pragma unroll
      for (int l = 0; l < 4; ++l){
        const float4 bb = *(const float4*)&wl[e0+l][e0j];
        #pragma unroll
        for (int u = 0; u < 4; ++u){
          const float av = l==0 ? a[u].x : l==1 ? a[u].y : l==2 ? a[u].z : a[u].w;
          acc[u] = f4fma(av, bb, acc[u]);
        }
      }
    }

    if (!half){
      u16* dst = (u16*)ws + (m ? EL_MAT : 0);   // m0: uk, m1: cv0
      #pragma unroll
      for (int u = 0; u < 4; ++u){
        const size_t t = (size_t)tb*64 + u*16 + i;
        const size_t fb = t*64 + e0j;
        float4 kb = make_float4(acc[u].x+bgr4.x, acc[u].y+bgr4.y, acc[u].z+bgr4.z, acc[u].w+bgr4.w);
        float mk = g16sum(kb.x+kb.y+kb.z+kb.w)*(1.0f/64.0f);
        float4 c0 = make_float4(kb.x-mk, kb.y-mk, kb.z-mk, kb.w-mk);
        float s00 = g16sum(dot4(c0,c0));
        float s0x = g16sum(dot4(c0,cx4));
        float s0y = g16sum(dot4(c0,cy4));
        ushort4 pu;
        if (m == 0){
          pu.x = f2bf(c0.x*lng4.x); pu.y = f2bf(c0.y*lng4.y);
          pu.z = f2bf(c0.z*lng4.z); pu.w = f2bf(c0.w*lng4.w);
        } else {
          pu.x = f2bf(c0.x); pu.y = f2bf(c0.y); pu.z = f2bf(c0.z); pu.w = f2bf(c0.w);
        }
        *(ushort4*)(dst + fb) = pu;
        if (j == 0){
          *(float4*)(ws + OFF_SCAL + t*8 + 4*m) = make_float4(s00, 2.0f*s0x, 2.0f*s0y, 0.0f);
        }
      }
    } else {
      u16* dst = (u16*)ws + (m ? 3*EL_MAT : 2*EL_MAT);  // m0: xkbg, m1: xvbg
      #pragma unroll
      for (int u = 0; u < 4; ++u){
        const size_t t = (size_t)tb*64 + u*16 + i;
        const size_t fb = t*64 + e0j;
        float4 xk = make_float4(acc[u].x+ge[u].x, acc[u].y+ge[u].y, acc[u].z+ge[u].z, acc[u].w+ge[u].w);
        float4 nk = ln16v(xk, lbg4, lbb4);
        ushort4 p4; p4.x = f2bf(nk.x); p4.y = f2bf(nk.y); p4.z = f2bf(nk.z); p4.w = f2bf(nk.w);
        *(ushort4*)(dst + fb) = p4;
      }
    }
    __syncthreads();
  }
}

// ---- k_init0: slots + iter0 prep + zero acc banks + GS. grid (5,NB) x 64 ----
__global__ __launch_bounds__(64) void k_init0(
    const float* __restrict__ sfg0, const float* __restrict__ sbg0,
    const float* __restrict__ pos0, const float* __restrict__ w_grid,
    const float* __restrict__ ln_fg_g, const float* __restrict__ ln_fg_b,
    const float* __restrict__ ln_q_g, const float* __restrict__ ln_q_b,
    const float* __restrict__ w_q,
    const float* __restrict__ ln_qbg_g, const float* __restrict__ ln_qbg_b,
    const float* __restrict__ w_qbg,
    const float* __restrict__ w_mlp_fg, const float* __restrict__ b_mlp_fg,
    const float* __restrict__ w_mlp_bg, const float* __restrict__ b_mlp_bg,
    float* __restrict__ ws)
{
  const int k = blockIdx.x, b = blockIdx.y, d = threadIdx.x;
  __shared__ __align__(16) float xl[64], hl[64];
  const float wgx = w_grid[4*d] - w_grid[4*d+2];
  const float wgy = w_grid[4*d+1] - w_grid[4*d+3];
  const float mgx = wavesum(wgx)*(1.0f/64.0f);
  const float mgy = wavesum(wgy)*(1.0f/64.0f);
  const float cx = wgx - mgx, cy = wgy - mgy;

  if (k < 4){
    const float sv = sfg0[k*64 + d];
    ws[OFF_SFG + b*256 + k*64 + d] = sv;
    if (d < 2) ws[OFF_POS + b*8 + k*2 + d] = pos0[k*2 + d];
    const float cxg = cx*ln_fg_g[d];
    const float cyg = cy*ln_fg_g[d];
    const float m = wavesum(sv)*(1.0f/64.0f);
    const float c = sv - m;
    const float var = wavesum(c*c)*(1.0f/64.0f);
    const float rs = rsqrtf(var + LNEPS);
    xl[d] = c*rs*ln_q_g[d] + ln_q_b[d];
    __syncthreads();
    const float q = rowdot64f(w_q + d*64, xl);
    hl[d] = q;
    const float qb = wavesum(q * b_mlp_fg[d]);
    __syncthreads();
    const float qw = coldot64(w_mlp_fg, hl, d);
    ws[OFF_QW + b*256 + k*64 + d] = qw;
    const float A  = wavesum(qw * cxg);
    const float Bv = wavesum(qw * cyg);
    const float Cv = wavesum(qw * ln_fg_b[d]) + qb;
    if (d == 0){
      float* abc = ws + OFF_ABC + (size_t)(b*4 + k)*4;
      abc[0] = A; abc[1] = Bv; abc[2] = Cv;
    }
  } else {
    const float sv = sbg0[d];
    ws[OFF_SBG + b*64 + d] = sv;
    float* accb = ws + OFF_ACC + (size_t)b*2*ACC_STRIDE;
    for (int i2 = d; i2 < 2*ACC_STRIDE; i2 += 64) accb[i2] = 0.0f;
    if (b == 0){
      const float gxx = wavesum(cx*cx);
      const float gyy = wavesum(cy*cy);
      const float gxy = wavesum(cx*cy);
      if (d == 0){ ws[OFF_GS] = gxx; ws[OFF_GS+1] = gyy; ws[OFF_GS+2] = 2.0f*gxy; }
    }
    const float m = wavesum(sv)*(1.0f/64.0f);
    const float c = sv - m;
    const float var = wavesum(c*c)*(1.0f/64.0f);
    const float rs = rsqrtf(var + LNEPS);
    xl[d] = c*rs*ln_qbg_g[d] + ln_qbg_b[d];
    __syncthreads();
    const float q = rowdot64f(w_qbg + d*64, xl);
    hl[d] = q;
    const float qb = wavesum(q * b_mlp_bg[d]);
    __syncthreads();
    const float qw = coldot64(w_mlp_bg, hl, d);
    ws[OFF_QWBG + b*64 + d] = qw;
    if (d == 0) ws[OFF_QBBG + b] = qb;
  }
}

// ---- main fused attention pass. grid (64,16) x 256, bf16 staging reads ----
template<int LAST>
__global__ __launch_bounds__(256) void k_main(
    const float* __restrict__ fc, const float* __restrict__ fcg,
    const float* __restrict__ fcb, const float* __restrict__ w_pos,
    float* __restrict__ ws, int bank)
{
  __shared__ float red[ACC_STRIDE];
  const int tid = threadIdx.x;
  const int b = blockIdx.y;
  for (int i2 = tid; i2 < ACC_STRIDE; i2 += 256) red[i2] = 0.0f;
  __syncthreads();

  const int G = tid >> 4;
  const int s = tid & 15;
  const int e0 = 4*s;

  float4 qw4[4]; float A[4], Bc[4], Cc[4], px[4], py[4];
  #pragma unroll
  for (int k = 0; k < 4; ++k){
    qw4[k] = *(const float4*)(ws + OFF_QW + (size_t)b*256 + k*64 + e0);
    const float* abc = ws + OFF_ABC + (size_t)(b*4 + k)*4;
    A[k] = abc[0]; Bc[k] = abc[1]; Cc[k] = abc[2];
    px[k] = ws[OFF_POS + b*8 + k*2 + 0];
    py[k] = ws[OFF_POS + b*8 + k*2 + 1];
  }
  const float4 qwbg4 = *(const float4*)(ws + OFF_QWBG + (size_t)b*64 + e0);
  const float qbbg = ws[OFF_QBBG + b];
  const float Gxx = ws[OFF_GS], Gyy = ws[OFF_GS+1], Gxy2 = ws[OFF_GS+2];

  const u16* ukh = (const u16*)ws;
  const u16* cvh = ukh + EL_MAT;
  const u16* xkh = cvh + EL_MAT;
  const u16* xvh = xkh + EL_MAT;

  float accY[4][4] = {};
  float accYbg[4] = {};
  float accS[5] = {};
  float accW0[4] = {}, accWx[4] = {}, accWy[4] = {};
  float accP[4][2] = {};
  float accT[4][2] = {};
  float accC[5] = {};

  const int nbase = blockIdx.x*64 + G*4;
  for (int i = 0; i < 4; ++i){
    const int n = nbase + i;
    const size_t tok = ((size_t)b << 12) + (size_t)n;
    const size_t rbase = tok*64 + e0;
    const ushort4 r0 = *(const ushort4*)(ukh + rbase);
    const ushort4 r1 = *(const ushort4*)(cvh + rbase);
    const ushort4 r2 = *(const ushort4*)(xkh + rbase);
    const ushort4 r3 = *(const ushort4*)(xvh + rbase);
    const float4 sA = *(const float4*)(ws + OFF_SCAL + tok*8);
    const float4 sB = *(const float4*)(ws + OFF_SCAL + tok*8 + 4);
    const float4 uk4  = make_float4(bf2f(r0.x), bf2f(r0.y), bf2f(r0.z), bf2f(r0.w));
    const float4 cv4  = make_float4(bf2f(r1.x), bf2f(r1.y), bf2f(r1.z), bf2f(r1.w));
    const float4 xkb4 = make_float4(bf2f(r2.x), bf2f(r2.y), bf2f(r2.z), bf2f(r2.w));
    const float4 xvb4 = make_float4(bf2f(r3.x), bf2f(r3.y), bf2f(r3.z), bf2f(r3.w));
    const float gx = -1.0f + (2.0f/63.0f)*(float)(n & 63);
    const float gy = -1.0f + (2.0f/63.0f)*(float)(n >> 6);
    float fcv = 0.0f, wpx = 0.0f, wpy = 0.0f;
    if (LAST){
      float v = (s < 8) ? fc[tok*8 + s] : 0.0f;
      float m8 = v;
      m8 += __shfl_xor(m8, 1); m8 += __shfl_xor(m8, 2); m8 += __shfl_xor(m8, 4);
      m8 *= 0.125f;
      const float cc = v - m8;
      float va = cc*cc;
      va += __shfl_xor(va, 1); va += __shfl_xor(va, 2); va += __shfl_xor(va, 4);
      va *= 0.125f;
      const float rs8 = rsqrtf(va + LNEPS);
      fcv = (s < 8) ? cc*rs8*fcg[s] + fcb[s] : 0.0f;
    } else {
      wpx = w_pos[n]; wpy = w_pos[NN + n];
    }

    float a0 = g16sum(dot4(xkb4, qwbg4));
    a0 = QSCALE*(a0 + qbbg);

    float a[4], rsv[4];
    #pragma unroll
    for (int k = 0; k < 4; ++k){
      const float rx = gx - px[k];
      const float ry = gy - py[k];
      const float rxy = rx*ry;
      float h1 = fmaf(rx, Gxx, sA.y);
      float h2 = fmaf(ry, Gyy, sA.z);
      float vk = fmaf(rx, h1, fmaf(ry, h2, sA.x));
      vk = fmaf(rxy, Gxy2, vk);
      const float rsk = rsqrtf(fmaf(vk, 1.0f/64.0f, LNEPS));
      float h1v = fmaf(rx, Gxx, sB.y);
      float h2v = fmaf(ry, Gyy, sB.z);
      float vv = fmaf(rx, h1v, fmaf(ry, h2v, sB.x));
      vv = fmaf(rxy, Gxy2, vv);
      rsv[k] = rsqrtf(fmaf(vv, 1.0f/64.0f, LNEPS));
      float dk = g16sum(dot4(uk4, qw4[k]));
      dk = fmaf(rx, A[k], dk);
      dk = fmaf(ry, Bc[k], dk);
      a[k] = QSCALE * fmaf(rsk, dk, Cc[k]);
    }
    const float mx = fmaxf(fmaxf(fmaxf(a[0],a[1]), fmaxf(a[2],a[3])), a0);
    float p0 = __expf(a0 - mx);
    float pk[4];
    float sum = p0;
    #pragma unroll
    for (int k = 0; k < 4; ++k){ pk[k] = __expf(a[k]-mx); sum += pk[k]; }
    const float inv = 1.0f/sum;
    p0 = fmaf(p0, inv, ATT_EPS);
    #pragma unroll
    for (int k = 0; k < 4; ++k) pk[k] = fmaf(pk[k], inv, ATT_EPS);

    accS[0] += p0;
    accYbg[0] = fmaf(p0, xvb4.x, accYbg[0]);
    accYbg[1] = fmaf(p0, xvb4.y, accYbg[1]);
    accYbg[2] = fmaf(p0, xvb4.z, accYbg[2]);
    accYbg[3] = fmaf(p0, xvb4.w, accYbg[3]);
    if (LAST) accC[0] = fmaf(p0, fcv, accC[0]);
    #pragma unroll
    for (int k = 0; k < 4; ++k){
      accS[k+1] += pk[k];
      const float prv = pk[k]*rsv[k];
      accY[k][0] = fmaf(prv, cv4.x, accY[k][0]);
      accY[k][1] = fmaf(prv, cv4.y, accY[k][1]);
      accY[k][2] = fmaf(prv, cv4.z, accY[k][2]);
      accY[k][3] = fmaf(prv, cv4.w, accY[k][3]);
      accW0[k] += prv;
      accWx[k] = fmaf(prv, gx, accWx[k]);
      accWy[k] = fmaf(prv, gy, accWy[k]);
      if (LAST){
        accC[k+1] = fmaf(pk[k], fcv, accC[k+1]);
      } else {
        accP[k][0] = fmaf(pk[k], gx, accP[k][0]);
        accP[k][1] = fmaf(pk[k], gy, accP[k][1]);
        accT[k][0] = fmaf(pk[k], wpx, accT[k][0]);
        accT[k][1] = fmaf(pk[k], wpy, accT[k][1]);
      }
    }
  }

  #pragma unroll
  for (int k = 0; k < 4; ++k){
    #pragma unroll
    for (int j2 = 0; j2 < 4; ++j2){ float x = accY[k][j2]; XRED(x); accY[k][j2] = x; }
    float x;
    x = accW0[k]; XRED(x); accW0[k] = x;
    x = accWx[k]; XRED(x); accWx[k] = x;
    x = accWy[k]; XRED(x); accWy[k] = x;
    x = accP[k][0]; XRED(x); accP[k][0] = x;
    x = accP[k][1]; XRED(x); accP[k][1] = x;
    x = accT[k][0]; XRED(x); accT[k][0] = x;
    x = accT[k][1]; XRED(x); accT[k][1] = x;
  }
  #pragma unroll
  for (int j2 = 0; j2 < 4; ++j2){ float x = accYbg[j2]; XRED(x); accYbg[j2] = x; }
  #pragma unroll
  for (int sl = 0; sl < 5; ++sl){ float x = accS[sl]; XRED(x); accS[sl] = x; }
  #pragma unroll
  for (int sl = 0; sl < 5; ++sl){ float x = accC[sl]; XRED(x); accC[sl] = x; }

  const bool g0 = (G & 3) == 0;
  if (g0){
    #pragma unroll
    for (int k = 0; k < 4; ++k){
      atomicAdd(&red[A_Y + k*64 + e0 + 0], accY[k][0]);
      atomicAdd(&red[A_Y + k*64 + e0 + 1], accY[k][1]);
      atomicAdd(&red[A_Y + k*64 + e0 + 2], accY[k][2]);
      atomicAdd(&red[A_Y + k*64 + e0 + 3], accY[k][3]);
    }
    atomicAdd(&red[A_YBG + e0 + 0], accYbg[0]);
    atomicAdd(&red[A_YBG + e0 + 1], accYbg[1]);
    atomicAdd(&red[A_YBG + e0 + 2], accYbg[2]);
    atomicAdd(&red[A_YBG + e0 + 3], accYbg[3]);
    if (s == 0){
      #pragma unroll
      for (int sl = 0; sl < 5; ++sl) atomicAdd(&red[A_S + sl], accS[sl]);
      #pragma unroll
      for (int k = 0; k < 4; ++k){
        atomicAdd(&red[A_W0 + k], accW0[k]);
        atomicAdd(&red[A_WX + k], accWx[k]);
        atomicAdd(&red[A_WY + k], accWy[k]);
      }
      if (!LAST){
        #pragma unroll
        for (int k = 0; k < 4; ++k){
          atomicAdd(&red[A_P + k*2 + 0], accP[k][0]);
          atomicAdd(&red[A_P + k*2 + 1], accP[k][1]);
          atomicAdd(&red[A_T + k*2 + 0], accT[k][0]);
          atomicAdd(&red[A_T + k*2 + 1], accT[k][1]);
        }
      }
    }
    if (LAST && s < 8){
      #pragma unroll
      for (int sl = 0; sl < 5; ++sl) atomicAdd(&red[A_C + sl*8 + s], accC[sl]);
    }
  }
  __syncthreads();
  float* gacc = ws + OFF_ACC + ((size_t)b*2 + bank)*ACC_STRIDE;
  for (int i2 = tid; i2 < ACC_STRIDE; i2 += 256){
    const float v = red[i2];
    if (v != 0.0f) atomicAdd(&gacc[i2], v);
  }
}

// ---- merged slot update + next-iter prep. grid (5,16) x 64 ----
__global__ __launch_bounds__(64) void k_slotupd(
    const float* __restrict__ w_mlp_fg, const float* __restrict__ b_mlp_fg,
    const float* __restrict__ w_mlp_bg, const float* __restrict__ b_mlp_bg,
    const float* __restrict__ gfg_wih, const float* __restrict__ gfg_whh,
    const float* __restrict__ gfg_bih, const float* __restrict__ gfg_bhh,
    const float* __restrict__ gbg_wih, const float* __restrict__ gbg_whh,
    const float* __restrict__ gbg_bih, const float* __restrict__ gbg_bhh,
    const float* __restrict__ ln_rfg_g, const float* __restrict__ ln_rfg_b,
    const float* __restrict__ w_rfg, const float* __restrict__ b_rfg,
    const float* __restrict__ ln_rbg_g, const float* __restrict__ ln_rbg_b,
    const float* __restrict__ w_rbg, const float* __restrict__ b_rbg,
    const float* __restrict__ b_pos,
    const float* __restrict__ ln_fg_g, const float* __restrict__ ln_fg_b,
    const float* __restrict__ ln_q_g, const float* __restrict__ ln_q_b,
    const float* __restrict__ w_q,
    const float* __restrict__ ln_qbg_g, const float* __restrict__ ln_qbg_b,
    const float* __restrict__ w_qbg,
    const float* __restrict__ w_grid,
    float* __restrict__ ws, int rbank)
{
  const int k = blockIdx.x, b = blockIdx.y, d = threadIdx.x;
  float* accR = ws + OFF_ACC + ((size_t)b*2 + rbank)*ACC_STRIDE;
  float* accZ = ws + OFF_ACC + ((size_t)b*2 + (rbank^1))*ACC_STRIDE;
  __shared__ __align__(16) float xl[64], hl[64], rl[64];

  if (k < 4){
    const float wgx = w_grid[4*d] - w_grid[4*d+2];
    const float wgy = w_grid[4*d+1] - w_grid[4*d+3];
    const float mgx = wavesum(wgx)*(1.0f/64.0f);
    const float mgy = wavesum(wgy)*(1.0f/64.0f);
    const float cxg = (wgx - mgx)*ln_fg_g[d];
    const float cyg = (wgy - mgy)*ln_fg_g[d];
    const float invS = 1.0f/accR[A_S + 1 + k];
    const float pxv = ws[OFF_POS + b*8 + k*2 + 0];
    const float pyv = ws[OFF_POS + b*8 + k*2 + 1];
    const float wxc = (accR[A_WX + k] - pxv*accR[A_W0 + k])*invS;
    const float wyc = (accR[A_WY + k] - pyv*accR[A_W0 + k])*invS;
    xl[d] = accR[A_Y + k*64 + d]*invS*ln_fg_g[d] + wxc*cxg + wyc*cyg + ln_fg_b[d];
    const float h = ws[OFF_SFG + b*256 + k*64 + d];
    hl[d] = h;
    __syncthreads();
    const float upd = b_mlp_fg[d] + rowdot64f(w_mlp_fg + d*64, xl);
    __syncthreads();
    xl[d] = upd;
    __syncthreads();
    const float gir = gfg_bih[d]     + rowdot64f(gfg_wih + d*64, xl);
    const float giz = gfg_bih[64+d]  + rowdot64f(gfg_wih + (64+d)*64, xl);
    const float gin = gfg_bih[128+d] + rowdot64f(gfg_wih + (128+d)*64, xl);
    const float ghr = gfg_bhh[d]     + rowdot64f(gfg_whh + d*64, hl);
    const float ghz = gfg_bhh[64+d]  + rowdot64f(gfg_whh + (64+d)*64, hl);
    const float ghn = gfg_bhh[128+d] + rowdot64f(gfg_whh + (128+d)*64, hl);
    const float r = 1.0f/(1.0f + expf(-(gir+ghr)));
    const float z = 1.0f/(1.0f + expf(-(giz+ghz)));
    const float nng = tanhf(fmaf(r, ghn, gin));
    const float hnew = (1.0f - z)*nng + z*h;
    const float m = wavesum(hnew)*(1.0f/64.0f);
    const float c = hnew - m;
    const float var = wavesum(c*c)*(1.0f/64.0f);
    const float rs = rsqrtf(var + LNEPS);
    rl[d] = c*rs*ln_rfg_g[d] + ln_rfg_b[d];
    __syncthreads();
    const float snew = hnew + b_rfg[d] + rowdot64f(w_rfg + d*64, rl);
    ws[OFF_SFG + b*256 + k*64 + d] = snew;
    if (d < 2){
      const float P = accR[A_P + k*2 + d]*invS;
      const float T = accR[A_T + k*2 + d]*invS;
      float pn = P + tanhf(T + b_pos[d])*0.2f;
      pn = fminf(1.0f, fmaxf(-1.0f, pn));
      ws[OFF_POS + b*8 + k*2 + d] = pn;
    }
    // ---- prep next iter ----
    const float m2 = wavesum(snew)*(1.0f/64.0f);
    const float c2 = snew - m2;
    const float var2 = wavesum(c2*c2)*(1.0f/64.0f);
    const float rs2 = rsqrtf(var2 + LNEPS);
    xl[d] = c2*rs2*ln_q_g[d] + ln_q_b[d];
    __syncthreads();
    const float q = rowdot64f(w_q + d*64, xl);
    hl[d] = q;
    const float qb = wavesum(q * b_mlp_fg[d]);
    __syncthreads();
    const float qw = coldot64(w_mlp_fg, hl, d);
    ws[OFF_QW + b*256 + k*64 + d] = qw;
    const float A  = wavesum(qw * cxg);
    const float Bv = wavesum(qw * cyg);
    const float Cv = wavesum(qw * ln_fg_b[d]) + qb;
    if (d == 0){
      float* abc = ws + OFF_ABC + (size_t)(b*4 + k)*4;
      abc[0] = A; abc[1] = Bv; abc[2] = Cv;
    }
  } else {
    const float invS = 1.0f/accR[A_S];
    xl[d] = accR[A_YBG + d]*invS;
    const float h = ws[OFF_SBG + b*64 + d];
    hl[d] = h;
    __syncthreads();
    const float upd = b_mlp_bg[d] + rowdot64f(w_mlp_bg + d*64, xl);
    __syncthreads();
    xl[d] = upd;
    __syncthreads();
    const float gir = gbg_bih[d]     + rowdot64f(gbg_wih + d*64, xl);
    const float giz = gbg_bih[64+d]  + rowdot64f(gbg_wih + (64+d)*64, xl);
    const float gin = gbg_bih[128+d] + rowdot64f(gbg_wih + (128+d)*64, xl);
    const float ghr = gbg_bhh[d]     + rowdot64f(gbg_whh + d*64, hl);
    const float ghz = gbg_bhh[64+d]  + rowdot64f(gbg_whh + (64+d)*64, hl);
    const float ghn = gbg_bhh[128+d] + rowdot64f(gbg_whh + (128+d)*64, hl);
    const float r = 1.0f/(1.0f + expf(-(gir+ghr)));
    const float z = 1.0f/(1.0f + expf(-(giz+ghz)));
    const float nng = tanhf(fmaf(r, ghn, gin));
    const float hnew = (1.0f - z)*nng + z*h;
    const float m = wavesum(hnew)*(1.0f/64.0f);
    const float c = hnew - m;
    const float var = wavesum(c*c)*(1.0f/64.0f);
    const float rs = rsqrtf(var + LNEPS);
    rl[d] = c*rs*ln_rbg_g[d] + ln_rbg_b[d];
    __syncthreads();
    const float snew = hnew + b_rbg[d] + rowdot64f(w_rbg + d*64, rl);
    ws[OFF_SBG + b*64 + d] = snew;
    // ---- prep next iter (bg) ----
    const float m2 = wavesum(snew)*(1.0f/64.0f);
    const float c2 = snew - m2;
    const float var2 = wavesum(c2*c2)*(1.0f/64.0f);
    const float rs2 = rsqrtf(var2 + LNEPS);
    xl[d] = c2*rs2*ln_qbg_g[d] + ln_qbg_b[d];
    __syncthreads();
    const float q = rowdot64f(w_qbg + d*64, xl);
    hl[d] = q;
    const float qb = wavesum(q * b_mlp_bg[d]);
    __syncthreads();
    const float qw = coldot64(w_mlp_bg, hl, d);
    ws[OFF_QWBG + b*64 + d] = qw;
    if (d == 0) ws[OFF_QBBG + b] = qb;
    for (int i2 = d; i2 < ACC_STRIDE; i2 += 64) accZ[i2] = 0.0f;
  }
}

// ---- final output. grid (5,16) x 64, reads bank 1 ----
__global__ __launch_bounds__(64) void k_final(
    const float* __restrict__ w_mlp_fg, const float* __restrict__ b_mlp_fg,
    const float* __restrict__ w_mlp_bg, const float* __restrict__ b_mlp_bg,
    const float* __restrict__ ln_fg_g, const float* __restrict__ ln_fg_b,
    const float* __restrict__ w_grid,
    const float* __restrict__ ws, float* __restrict__ out)
{
  const int k = blockIdx.x, b = blockIdx.y, d = threadIdx.x;
  const float* acc = ws + OFF_ACC + ((size_t)b*2 + 1)*ACC_STRIDE;
  __shared__ __align__(16) float xl[64];
  if (k < 4){
    const float wgx = w_grid[4*d] - w_grid[4*d+2];
    const float wgy = w_grid[4*d+1] - w_grid[4*d+3];
    const float mgx = wavesum(wgx)*(1.0f/64.0f);
    const float mgy = wavesum(wgy)*(1.0f/64.0f);
    const float cxg = (wgx - mgx)*ln_fg_g[d];
    const float cyg = (wgy - mgy)*ln_fg_g[d];
    const float invS = 1.0f/acc[A_S + 1 + k];
    const float pxv = ws[OFF_POS + b*8 + k*2 + 0];
    const float pyv = ws[OFF_POS + b*8 + k*2 + 1];
    const float wxc = (acc[A_WX + k] - pxv*acc[A_W0 + k])*invS;
    const float wyc = (acc[A_WY + k] - pyv*acc[A_W0 + k])*invS;
    xl[d] = acc[A_Y + k*64 + d]*invS*ln_fg_g[d] + wxc*cxg + wyc*cyg + ln_fg_b[d];
    __syncthreads();
    const float o = b_mlp_fg[d] + rowdot64f(w_mlp_fg + d*64, xl);
    out[(size_t)(b*5 + 1 + k)*72 + d] = o;
    if (d < 8) out[(size_t)(b*5 + 1 + k)*72 + 64 + d] = acc[A_C + (k+1)*8 + d]*invS;
  } else {
    const float invS = 1.0f/acc[A_S];
    xl[d] = acc[A_YBG + d]*invS;
    __syncthreads();
    const float o = b_mlp_bg[d] + rowdot64f(w_mlp_bg + d*64, xl);
    out[(size_t)(b*5)*72 + d] = o;
    if (d < 8) out[(size_t)(b*5)*72 + 64 + d] = acc[A_C + d]*invS;
  }
}

extern "C" void kernel_launch(void* const* d_in, const int* in_sizes, int n_in,
                              void* d_out, int out_size, void* d_ws, size_t ws_size,
                              hipStream_t stream)
{
  const float* feat          = (const float*)d_in[0];
  const float* feat_color    = (const float*)d_in[1];
  const float* w_grid        = (const float*)d_in[2];
  const float* b_grid        = (const float*)d_in[3];
  const float* w_kfg         = (const float*)d_in[4];
  const float* w_vfg         = (const float*)d_in[5];
  const float* w_kbg         = (const float*)d_in[6];
  const float* w_vbg         = (const float*)d_in[7];
  const float* ln_fg_g       = (const float*)d_in[8];
  const float* ln_fg_b       = (const float*)d_in[9];
  const float* w_mlp_fg      = (const float*)d_in[10];
  const float* b_mlp_fg      = (const float*)d_in[11];
  const float* ln_bg_g       = (const float*)d_in[12];
  const float* ln_bg_b       = (const float*)d_in[13];
  const float* w_mlp_bg      = (const float*)d_in[14];
  const float* b_mlp_bg      = (const float*)d_in[15];
  const float* slots_init_fg = (const float*)d_in[16];
  const float* slots_init_bg = (const float*)d_in[17];
  const float* fg_position   = (const float*)d_in[18];
  const float* w_pos         = (const float*)d_in[19];
  const float* b_pos         = (const float*)d_in[20];
  const float* ln_q_g        = (const float*)d_in[21];
  const float* ln_q_b        = (const float*)d_in[22];
  const float* w_q           = (const float*)d_in[23];
  const float* ln_qbg_g      = (const float*)d_in[24];
  const float* ln_qbg_b      = (const float*)d_in[25];
  const float* w_qbg         = (const float*)d_in[26];
  const float* gfg_wih       = (const float*)d_in[27];
  const float* gfg_whh       = (const float*)d_in[28];
  const float* gfg_bih       = (const float*)d_in[29];
  const float* gfg_bhh       = (const float*)d_in[30];
  const float* gbg_wih       = (const float*)d_in[31];
  const float* gbg_whh       = (const float*)d_in[32];
  const float* gbg_bih       = (const float*)d_in[33];
  const float* gbg_bhh       = (const float*)d_in[34];
  const float* ln_rfg_g      = (const float*)d_in[35];
  const float* ln_rfg_b      = (const float*)d_in[36];
  const float* w_rfg         = (const float*)d_in[37];
  const float* b_rfg         = (const float*)d_in[38];
  const float* ln_rbg_g      = (const float*)d_in[39];
  const float* ln_rbg_b      = (const float*)d_in[40];
  const float* w_rbg         = (const float*)d_in[41];
  const float* b_rbg         = (const float*)d_in[42];
  const float* ln_feat_g     = (const float*)d_in[43];
  const float* ln_feat_b     = (const float*)d_in[44];
  const float* ln_fc_g       = (const float*)d_in[45];
  const float* ln_fc_b       = (const float*)d_in[46];
  float* ws  = (float*)d_ws;
  float* out = (float*)d_out;

  hipLaunchKernelGGL(k_init0, dim3(5,16), dim3(64), 0, stream,
                     slots_init_fg, slots_init_bg, fg_position, w_grid,
                     ln_fg_g, ln_fg_b, ln_q_g, ln_q_b, w_q,
                     ln_qbg_g, ln_qbg_b, w_qbg,
                     w_mlp_fg, b_mlp_fg, w_mlp_bg, b_mlp_bg, ws);
  hipLaunchKernelGGL(k_pre, dim3(2048), dim3(256), 0, stream,
                     feat, w_kfg, w_vfg, w_kbg, w_vbg, w_grid, b_grid,
                     ln_feat_g, ln_feat_b, ln_bg_g, ln_bg_b, ln_fg_g, ws);
  for (int it = 0; it < NITER; ++it){
    const int bank = it & 1;
    if (it < NITER-1){
      hipLaunchKernelGGL((k_main<0>), dim3(64,16), dim3(256), 0, stream,
                         feat_color, ln_fc_g, ln_fc_b, w_pos, ws, bank);
      hipLaunchKernelGGL(k_slotupd, dim3(5,16), dim3(64), 0, stream,
                         w_mlp_fg, b_mlp_fg, w_mlp_bg, b_mlp_bg,
                         gfg_wih, gfg_whh, gfg_bih, gfg_bhh,
                         gbg_wih, gbg_whh, gbg_bih, gbg_bhh,
                         ln_rfg_g, ln_rfg_b, w_rfg, b_rfg,
                         ln_rbg_g, ln_rbg_b, w_rbg, b_rbg,
                         b_pos, ln_fg_g, ln_fg_b,
                         ln_q_g, ln_q_b, w_q, ln_qbg_g, ln_qbg_b, w_qbg,
                         w_grid, ws, bank);
    } else {
      hipLaunchKernelGGL((k_main<1>), dim3(64,16), dim3(256), 0, stream,
                         feat_color, ln_fc_g, ln_fc_b, w_pos, ws, bank);
      hipLaunchKernelGGL(k_final, dim3(5,16), dim3(64), 0, stream,
                         w_mlp_fg, b_mlp_fg, w_mlp_bg, b_mlp_bg,
                         ln_fg_g, ln_fg_b, w_grid, ws, out);
    }
  }
}

// Round 11
// 188.909 us; speedup vs baseline: 3.6280x; 1.0513x over previous
//
#include <hip/hip_runtime.h>
#include <math.h>
#include <stddef.h>

#define NB 16
#define ND 64
#define NN 4096
#define NCD 8
#define NITER 4
#define ATT_EPS 1e-8f
#define LNEPS 1e-5f
#define QSCALE 0.125f

typedef unsigned short u16;
typedef unsigned int u32;

// ---- workspace layout ----
static constexpr size_t EL_MAT   = (size_t)NB*NN*ND;           // elems per bf16 matrix
static constexpr size_t OFF_SCAL = 2*EL_MAT;                   // (floats) per-token 8 fp32 scalars
static constexpr size_t OFF_ACC  = OFF_SCAL + (size_t)NB*NN*8; // NB * 2 banks * 448
static constexpr size_t OFF_SFG  = OFF_ACC  + (size_t)NB*2*448;
static constexpr size_t OFF_SBG  = OFF_SFG  + (size_t)NB*256;
static constexpr size_t OFF_POS  = OFF_SBG  + (size_t)NB*64;
static constexpr size_t OFF_QW   = OFF_POS  + (size_t)NB*8;
static constexpr size_t OFF_QWBG = OFF_QW   + (size_t)NB*256;
static constexpr size_t OFF_QBBG = OFF_QWBG + (size_t)NB*64;
static constexpr size_t OFF_ABC  = OFF_QBBG + (size_t)NB;      // per (b,k): A,B,C,pad
static constexpr size_t OFF_GS   = OFF_ABC  + (size_t)NB*16;   // Gxx,Gyy,2*Gxy

#define A_S 0
#define A_W0 8
#define A_WX 12
#define A_WY 16
#define A_P 24
#define A_T 32
#define A_C 40
#define A_Y 80
#define A_YBG 336
#define ACC_STRIDE 448

// ---- helpers ----
__device__ __forceinline__ u16 f2bf(float f){
  u32 u = __float_as_uint(f);
  u32 r = (u + 0x7FFFu + ((u >> 16) & 1u)) >> 16;
  return (u16)r;
}
__device__ __forceinline__ float bf2f(u16 h){ return __uint_as_float(((u32)h) << 16); }

__device__ __forceinline__ float g16sum(float x){
  x += __shfl_xor(x, 1);
  x += __shfl_xor(x, 2);
  x += __shfl_xor(x, 4);
  x += __shfl_xor(x, 8);
  return x;
}
__device__ __forceinline__ float wavesum(float x){
  x += __shfl_xor(x, 1);  x += __shfl_xor(x, 2);
  x += __shfl_xor(x, 4);  x += __shfl_xor(x, 8);
  x += __shfl_xor(x, 16); x += __shfl_xor(x, 32);
  return x;
}
__device__ __forceinline__ float4 f4fma(float a, float4 w, float4 c){
  c.x = fmaf(a, w.x, c.x); c.y = fmaf(a, w.y, c.y);
  c.z = fmaf(a, w.z, c.z); c.w = fmaf(a, w.w, c.w);
  return c;
}
__device__ __forceinline__ float dot4(float4 a, float4 b){
  return fmaf(a.x,b.x, fmaf(a.y,b.y, fmaf(a.z,b.z, a.w*b.w)));
}
__device__ __forceinline__ float4 ln16v(float4 x, float4 g, float4 bb){
  float m = g16sum(x.x + x.y + x.z + x.w) * (1.0f/64.0f);
  float4 c = make_float4(x.x - m, x.y - m, x.z - m, x.w - m);
  float var = g16sum(c.x*c.x + c.y*c.y + c.z*c.z + c.w*c.w) * (1.0f/64.0f);
  float rs = rsqrtf(var + LNEPS);
  return make_float4(c.x*rs*g.x + bb.x, c.y*rs*g.y + bb.y,
                     c.z*rs*g.z + bb.z, c.w*rs*g.w + bb.w);
}
__device__ __forceinline__ float rowdot64f(const float* __restrict__ W, const float* x){
  const float4* w4 = (const float4*)W;
  const float4* x4 = (const float4*)x;
  float s0=0.f, s1=0.f, s2=0.f, s3=0.f;
  #pragma unroll
  for (int t = 0; t < 4; ++t){
    float4 w, xx;
    w = w4[t];     xx = x4[t];     s0 = fmaf(w.x,xx.x, fmaf(w.y,xx.y, fmaf(w.z,xx.z, fmaf(w.w,xx.w, s0))));
    w = w4[4+t];   xx = x4[4+t];   s1 = fmaf(w.x,xx.x, fmaf(w.y,xx.y, fmaf(w.z,xx.z, fmaf(w.w,xx.w, s1))));
    w = w4[8+t];   xx = x4[8+t];   s2 = fmaf(w.x,xx.x, fmaf(w.y,xx.y, fmaf(w.z,xx.z, fmaf(w.w,xx.w, s2))));
    w = w4[12+t];  xx = x4[12+t];  s3 = fmaf(w.x,xx.x, fmaf(w.y,xx.y, fmaf(w.z,xx.z, fmaf(w.w,xx.w, s3))));
  }
  return (s0+s1)+(s2+s3);
}
__device__ __forceinline__ float coldot64(const float* __restrict__ W, const float* x, int d){
  float s0=0.f, s1=0.f, s2=0.f, s3=0.f;
  #pragma unroll
  for (int t = 0; t < 16; ++t){
    s0 = fmaf(x[t],      W[(t)*64+d],      s0);
    s1 = fmaf(x[16+t],   W[(16+t)*64+d],   s1);
    s2 = fmaf(x[32+t],   W[(32+t)*64+d],   s2);
    s3 = fmaf(x[48+t],   W[(48+t)*64+d],   s3);
  }
  return (s0+s1)+(s2+s3);
}
#define XRED(x) do { x += __shfl_xor(x, 16); x += __shfl_xor(x, 32); } while (0)

// ---- k_pre: 512 threads, 128 tokens/block, 64KB LDS (2 blk/CU = 4 waves/SIMD),
// dual-matrix single pass (r8's proven 68-VGPR inner loop), XOR-swizzled LDS
// (unpadded [..][64] would be 4-way conflicted on a-loads; swizzle block^row&7
// applied on BOTH write and read — same involution both sides). ----
__global__ __launch_bounds__(512) void k_pre(
    const float* __restrict__ feat,
    const float* __restrict__ w_kfg, const float* __restrict__ w_vfg,
    const float* __restrict__ w_kbg, const float* __restrict__ w_vbg,
    const float* __restrict__ w_grid, const float* __restrict__ b_grid,
    const float* __restrict__ ln_feat_g, const float* __restrict__ ln_feat_b,
    const float* __restrict__ ln_bg_g, const float* __restrict__ ln_bg_b,
    const float* __restrict__ ln_fg_g,
    float* __restrict__ ws)
{
  __shared__ __align__(16) float fl[128][64];     // 32 KB, swizzled
  __shared__ __align__(16) float wl[2][64][64];   // 32 KB, swizzled: wl[m][e][d]=W_m[d][e]
  const int tid  = threadIdx.x;
  const int bid  = blockIdx.x;
  const int half = bid >> 9;         // 0 = fg pair, 1 = bg pair
  const int tb   = bid & 511;        // token-block (128 tokens)
  const int G2   = tid >> 4;         // 0..31 token-group
  const int j    = tid & 15;         // 0..15 col-group
  const int e0j  = 4*j;
  const float* wA = half ? w_kbg : w_kfg;
  const float* wB = half ? w_vbg : w_vfg;

  // stage weights transposed (both matrices), swizzled
  #pragma unroll
  for (int it = 0; it < 4; ++it){
    const int f = it*512 + tid;       // float4 id 0..2047
    const int m = f >> 10;
    const int r = f & 1023;
    const int dd = r >> 4;            // source row (d)
    const int s4 = r & 15;            // element block
    const float* src = m ? wB : wA;
    const float4 wv = *(const float4*)(src + dd*64 + 4*s4);
    const int blk = dd >> 2, w4i = dd & 3;
    #pragma unroll
    for (int c = 0; c < 4; ++c){
      const int row = 4*s4 + c;
      const float v = c==0 ? wv.x : c==1 ? wv.y : c==2 ? wv.z : wv.w;
      wl[m][row][4*(blk ^ (row & 7)) + w4i] = v;
    }
  }
  // stage feat tile with LN, swizzled
  {
    const float4 lfg4 = *(const float4*)(ln_feat_g + e0j);
    const float4 lfb4 = *(const float4*)(ln_feat_b + e0j);
    #pragma unroll
    for (int u = 0; u < 4; ++u){
      const int tok = u*32 + G2;
      const size_t gb = ((size_t)tb*128 + tok)*64 + e0j;
      const float4 f4 = *(const float4*)(feat + gb);
      *(float4*)&fl[tok][4*(j ^ (tok & 7))] = ln16v(f4, lfg4, lfb4);
    }
  }
  __syncthreads();

  float4 acc0[4], acc1[4];
  #pragma unroll
  for (int u = 0; u < 4; ++u){ acc0[u] = make_float4(0,0,0,0); acc1[u] = acc0[u]; }
  for (int e0 = 0; e0 < 64; e0 += 4){
    const int eb = e0 >> 2;
    float4 a[4];
    #pragma unroll
    for (int u = 0; u < 4; ++u){
      const int row = u*32 + G2;
      a[u] = *(const float4*)&fl[row][4*(eb ^ (row & 7))];
    }
    #pragma unroll
    for (int l = 0; l < 4; ++l){
      const int row = e0 + l;
      const int cb = 4*(j ^ (row & 7));
      const float4 b0 = *(const float4*)&wl[0][row][cb];
      const float4 b1 = *(const float4*)&wl[1][row][cb];
      #pragma unroll
      for (int u = 0; u < 4; ++u){
        const float av = l==0 ? a[u].x : l==1 ? a[u].y : l==2 ? a[u].z : a[u].w;
        acc0[u] = f4fma(av, b0, acc0[u]);
        acc1[u] = f4fma(av, b1, acc1[u]);
      }
    }
  }

  const float4 bgr4 = *(const float4*)(b_grid + e0j);
  float4 wgx4, wgy4;
  {
    float4 w0 = *(const float4*)(w_grid + (e0j+0)*4);
    float4 w1 = *(const float4*)(w_grid + (e0j+1)*4);
    float4 w2 = *(const float4*)(w_grid + (e0j+2)*4);
    float4 w3 = *(const float4*)(w_grid + (e0j+3)*4);
    wgx4 = make_float4(w0.x-w0.z, w1.x-w1.z, w2.x-w2.z, w3.x-w3.z);
    wgy4 = make_float4(w0.y-w0.w, w1.y-w1.w, w2.y-w2.w, w3.y-w3.w);
  }

  if (!half){
    // fg: centered stats + uk = c0*g (bf16), cv0 raw centered (bf16), scal fp32
    const float4 lng4 = *(const float4*)(ln_fg_g + e0j);
    const float mx = g16sum(wgx4.x+wgx4.y+wgx4.z+wgx4.w)*(1.0f/64.0f);
    const float my = g16sum(wgy4.x+wgy4.y+wgy4.z+wgy4.w)*(1.0f/64.0f);
    const float4 cx4 = make_float4(wgx4.x-mx, wgx4.y-mx, wgx4.z-mx, wgx4.w-mx);
    const float4 cy4 = make_float4(wgy4.x-my, wgy4.y-my, wgy4.z-my, wgy4.w-my);
    u16* ukh = (u16*)ws;
    u16* cvh = ukh + EL_MAT;
    #pragma unroll
    for (int u = 0; u < 4; ++u){
      const size_t t = (size_t)tb*128 + u*32 + G2;
      const size_t fb = t*64 + e0j;
      // k-side
      float4 kb = make_float4(acc0[u].x+bgr4.x, acc0[u].y+bgr4.y, acc0[u].z+bgr4.z, acc0[u].w+bgr4.w);
      float mk = g16sum(kb.x+kb.y+kb.z+kb.w)*(1.0f/64.0f);
      float4 c0 = make_float4(kb.x-mk, kb.y-mk, kb.z-mk, kb.w-mk);
      float s00 = g16sum(dot4(c0,c0));
      float s0x = g16sum(dot4(c0,cx4));
      float s0y = g16sum(dot4(c0,cy4));
      ushort4 pu;
      pu.x = f2bf(c0.x*lng4.x); pu.y = f2bf(c0.y*lng4.y);
      pu.z = f2bf(c0.z*lng4.z); pu.w = f2bf(c0.w*lng4.w);
      *(ushort4*)(ukh + fb) = pu;
      // v-side
      float4 vb = make_float4(acc1[u].x+bgr4.x, acc1[u].y+bgr4.y, acc1[u].z+bgr4.z, acc1[u].w+bgr4.w);
      float mv = g16sum(vb.x+vb.y+vb.z+vb.w)*(1.0f/64.0f);
      float4 cv = make_float4(vb.x-mv, vb.y-mv, vb.z-mv, vb.w-mv);
      float sv0 = g16sum(dot4(cv,cv));
      float svx = g16sum(dot4(cv,cx4));
      float svy = g16sum(dot4(cv,cy4));
      ushort4 pv;
      pv.x = f2bf(cv.x); pv.y = f2bf(cv.y); pv.z = f2bf(cv.z); pv.w = f2bf(cv.w);
      *(ushort4*)(cvh + fb) = pv;
      if (j == 0){
        float* sc = ws + OFF_SCAL + t*8;
        *(float4*)(sc)   = make_float4(s00, 2.0f*s0x, 2.0f*s0y, 0.0f);
        *(float4*)(sc+4) = make_float4(sv0, 2.0f*svx, 2.0f*svy, 0.0f);
      }
    }
  } else {
    // bg: ge + LN(ln_bg), bf16 out (ge computed inline — keeping it pre-loop
    // cost +40 VGPR and occupancy in r10)
    const float4 lbg4 = *(const float4*)(ln_bg_g + e0j);
    const float4 lbb4 = *(const float4*)(ln_bg_b + e0j);
    u16* xkh = (u16*)ws + 2*EL_MAT;
    u16* xvh = (u16*)ws + 3*EL_MAT;
    #pragma unroll
    for (int u = 0; u < 4; ++u){
      const size_t t = (size_t)tb*128 + u*32 + G2;
      const int n = (int)(t & (NN-1));
      const float gx = -1.0f + (2.0f/63.0f)*(float)(n & 63);
      const float gy = -1.0f + (2.0f/63.0f)*(float)(n >> 6);
      const float4 ge = make_float4(
          fmaf(gx, wgx4.x, fmaf(gy, wgy4.x, bgr4.x)),
          fmaf(gx, wgx4.y, fmaf(gy, wgy4.y, bgr4.y)),
          fmaf(gx, wgx4.z, fmaf(gy, wgy4.z, bgr4.z)),
          fmaf(gx, wgx4.w, fmaf(gy, wgy4.w, bgr4.w)));
      const size_t fb = t*64 + e0j;
      float4 xk = make_float4(acc0[u].x+ge.x, acc0[u].y+ge.y, acc0[u].z+ge.z, acc0[u].w+ge.w);
      float4 nk = ln16v(xk, lbg4, lbb4);
      ushort4 pk4; pk4.x = f2bf(nk.x); pk4.y = f2bf(nk.y); pk4.z = f2bf(nk.z); pk4.w = f2bf(nk.w);
      *(ushort4*)(xkh + fb) = pk4;
      float4 xv = make_float4(acc1[u].x+ge.x, acc1[u].y+ge.y, acc1[u].z+ge.z, acc1[u].w+ge.w);
      float4 nv = ln16v(xv, lbg4, lbb4);
      ushort4 pv4; pv4.x = f2bf(nv.x); pv4.y = f2bf(nv.y); pv4.z = f2bf(nv.z); pv4.w = f2bf(nv.w);
      *(ushort4*)(xvh + fb) = pv4;
    }
  }
}

// ---- k_init0: slots + iter0 prep + zero acc banks + GS. grid (5,NB) x 64 ----
__global__ __launch_bounds__(64) void k_init0(
    const float* __restrict__ sfg0, const float* __restrict__ sbg0,
    const float* __restrict__ pos0, const float* __restrict__ w_grid,
    const float* __restrict__ ln_fg_g, const float* __restrict__ ln_fg_b,
    const float* __restrict__ ln_q_g, const float* __restrict__ ln_q_b,
    const float* __restrict__ w_q,
    const float* __restrict__ ln_qbg_g, const float* __restrict__ ln_qbg_b,
    const float* __restrict__ w_qbg,
    const float* __restrict__ w_mlp_fg, const float* __restrict__ b_mlp_fg,
    const float* __restrict__ w_mlp_bg, const float* __restrict__ b_mlp_bg,
    float* __restrict__ ws)
{
  const int k = blockIdx.x, b = blockIdx.y, d = threadIdx.x;
  __shared__ __align__(16) float xl[64], hl[64];
  const float wgx = w_grid[4*d] - w_grid[4*d+2];
  const float wgy = w_grid[4*d+1] - w_grid[4*d+3];
  const float mgx = wavesum(wgx)*(1.0f/64.0f);
  const float mgy = wavesum(wgy)*(1.0f/64.0f);
  const float cx = wgx - mgx, cy = wgy - mgy;

  if (k < 4){
    const float sv = sfg0[k*64 + d];
    ws[OFF_SFG + b*256 + k*64 + d] = sv;
    if (d < 2) ws[OFF_POS + b*8 + k*2 + d] = pos0[k*2 + d];
    const float cxg = cx*ln_fg_g[d];
    const float cyg = cy*ln_fg_g[d];
    const float m = wavesum(sv)*(1.0f/64.0f);
    const float c = sv - m;
    const float var = wavesum(c*c)*(1.0f/64.0f);
    const float rs = rsqrtf(var + LNEPS);
    xl[d] = c*rs*ln_q_g[d] + ln_q_b[d];
    __syncthreads();
    const float q = rowdot64f(w_q + d*64, xl);
    hl[d] = q;
    const float qb = wavesum(q * b_mlp_fg[d]);
    __syncthreads();
    const float qw = coldot64(w_mlp_fg, hl, d);
    ws[OFF_QW + b*256 + k*64 + d] = qw;
    const float A  = wavesum(qw * cxg);
    const float Bv = wavesum(qw * cyg);
    const float Cv = wavesum(qw * ln_fg_b[d]) + qb;
    if (d == 0){
      float* abc = ws + OFF_ABC + (size_t)(b*4 + k)*4;
      abc[0] = A; abc[1] = Bv; abc[2] = Cv;
    }
  } else {
    const float sv = sbg0[d];
    ws[OFF_SBG + b*64 + d] = sv;
    float* accb = ws + OFF_ACC + (size_t)b*2*ACC_STRIDE;
    for (int i2 = d; i2 < 2*ACC_STRIDE; i2 += 64) accb[i2] = 0.0f;
    if (b == 0){
      const float gxx = wavesum(cx*cx);
      const float gyy = wavesum(cy*cy);
      const float gxy = wavesum(cx*cy);
      if (d == 0){ ws[OFF_GS] = gxx; ws[OFF_GS+1] = gyy; ws[OFF_GS+2] = 2.0f*gxy; }
    }
    const float m = wavesum(sv)*(1.0f/64.0f);
    const float c = sv - m;
    const float var = wavesum(c*c)*(1.0f/64.0f);
    const float rs = rsqrtf(var + LNEPS);
    xl[d] = c*rs*ln_qbg_g[d] + ln_qbg_b[d];
    __syncthreads();
    const float q = rowdot64f(w_qbg + d*64, xl);
    hl[d] = q;
    const float qb = wavesum(q * b_mlp_bg[d]);
    __syncthreads();
    const float qw = coldot64(w_mlp_bg, hl, d);
    ws[OFF_QWBG + b*64 + d] = qw;
    if (d == 0) ws[OFF_QBBG + b] = qb;
  }
}

// ---- main fused attention pass. grid (64,16) x 256, bf16 staging reads ----
template<int LAST>
__global__ __launch_bounds__(256) void k_main(
    const float* __restrict__ fc, const float* __restrict__ fcg,
    const float* __restrict__ fcb, const float* __restrict__ w_pos,
    float* __restrict__ ws, int bank)
{
  __shared__ float red[ACC_STRIDE];
  const int tid = threadIdx.x;
  const int b = blockIdx.y;
  for (int i2 = tid; i2 < ACC_STRIDE; i2 += 256) red[i2] = 0.0f;
  __syncthreads();

  const int G = tid >> 4;
  const int s = tid & 15;
  const int e0 = 4*s;

  float4 qw4[4]; float A[4], Bc[4], Cc[4], px[4], py[4];
  #pragma unroll
  for (int k = 0; k < 4; ++k){
    qw4[k] = *(const float4*)(ws + OFF_QW + (size_t)b*256 + k*64 + e0);
    const float* abc = ws + OFF_ABC + (size_t)(b*4 + k)*4;
    A[k] = abc[0]; Bc[k] = abc[1]; Cc[k] = abc[2];
    px[k] = ws[OFF_POS + b*8 + k*2 + 0];
    py[k] = ws[OFF_POS + b*8 + k*2 + 1];
  }
  const float4 qwbg4 = *(const float4*)(ws + OFF_QWBG + (size_t)b*64 + e0);
  const float qbbg = ws[OFF_QBBG + b];
  const float Gxx = ws[OFF_GS], Gyy = ws[OFF_GS+1], Gxy2 = ws[OFF_GS+2];

  const u16* ukh = (const u16*)ws;
  const u16* cvh = ukh + EL_MAT;
  const u16* xkh = cvh + EL_MAT;
  const u16* xvh = xkh + EL_MAT;

  float accY[4][4] = {};
  float accYbg[4] = {};
  float accS[5] = {};
  float accW0[4] = {}, accWx[4] = {}, accWy[4] = {};
  float accP[4][2] = {};
  float accT[4][2] = {};
  float accC[5] = {};

  const int nbase = blockIdx.x*64 + G*4;
  for (int i = 0; i < 4; ++i){
    const int n = nbase + i;
    const size_t tok = ((size_t)b << 12) + (size_t)n;
    const size_t rbase = tok*64 + e0;
    const ushort4 r0 = *(const ushort4*)(ukh + rbase);
    const ushort4 r1 = *(const ushort4*)(cvh + rbase);
    const ushort4 r2 = *(const ushort4*)(xkh + rbase);
    const ushort4 r3 = *(const ushort4*)(xvh + rbase);
    const float4 sA = *(const float4*)(ws + OFF_SCAL + tok*8);
    const float4 sB = *(const float4*)(ws + OFF_SCAL + tok*8 + 4);
    const float4 uk4  = make_float4(bf2f(r0.x), bf2f(r0.y), bf2f(r0.z), bf2f(r0.w));
    const float4 cv4  = make_float4(bf2f(r1.x), bf2f(r1.y), bf2f(r1.z), bf2f(r1.w));
    const float4 xkb4 = make_float4(bf2f(r2.x), bf2f(r2.y), bf2f(r2.z), bf2f(r2.w));
    const float4 xvb4 = make_float4(bf2f(r3.x), bf2f(r3.y), bf2f(r3.z), bf2f(r3.w));
    const float gx = -1.0f + (2.0f/63.0f)*(float)(n & 63);
    const float gy = -1.0f + (2.0f/63.0f)*(float)(n >> 6);
    float fcv = 0.0f, wpx = 0.0f, wpy = 0.0f;
    if (LAST){
      float v = (s < 8) ? fc[tok*8 + s] : 0.0f;
      float m8 = v;
      m8 += __shfl_xor(m8, 1); m8 += __shfl_xor(m8, 2); m8 += __shfl_xor(m8, 4);
      m8 *= 0.125f;
      const float cc = v - m8;
      float va = cc*cc;
      va += __shfl_xor(va, 1); va += __shfl_xor(va, 2); va += __shfl_xor(va, 4);
      va *= 0.125f;
      const float rs8 = rsqrtf(va + LNEPS);
      fcv = (s < 8) ? cc*rs8*fcg[s] + fcb[s] : 0.0f;
    } else {
      wpx = w_pos[n]; wpy = w_pos[NN + n];
    }

    float a0 = g16sum(dot4(xkb4, qwbg4));
    a0 = QSCALE*(a0 + qbbg);

    float a[4], rsv[4];
    #pragma unroll
    for (int k = 0; k < 4; ++k){
      const float rx = gx - px[k];
      const float ry = gy - py[k];
      const float rxy = rx*ry;
      float h1 = fmaf(rx, Gxx, sA.y);
      float h2 = fmaf(ry, Gyy, sA.z);
      float vk = fmaf(rx, h1, fmaf(ry, h2, sA.x));
      vk = fmaf(rxy, Gxy2, vk);
      const float rsk = rsqrtf(fmaf(vk, 1.0f/64.0f, LNEPS));
      float h1v = fmaf(rx, Gxx, sB.y);
      float h2v = fmaf(ry, Gyy, sB.z);
      float vv = fmaf(rx, h1v, fmaf(ry, h2v, sB.x));
      vv = fmaf(rxy, Gxy2, vv);
      rsv[k] = rsqrtf(fmaf(vv, 1.0f/64.0f, LNEPS));
      float dk = g16sum(dot4(uk4, qw4[k]));
      dk = fmaf(rx, A[k], dk);
      dk = fmaf(ry, Bc[k], dk);
      a[k] = QSCALE * fmaf(rsk, dk, Cc[k]);
    }
    const float mx = fmaxf(fmaxf(fmaxf(a[0],a[1]), fmaxf(a[2],a[3])), a0);
    float p0 = __expf(a0 - mx);
    float pk[4];
    float sum = p0;
    #pragma unroll
    for (int k = 0; k < 4; ++k){ pk[k] = __expf(a[k]-mx); sum += pk[k]; }
    const float inv = 1.0f/sum;
    p0 = fmaf(p0, inv, ATT_EPS);
    #pragma unroll
    for (int k = 0; k < 4; ++k) pk[k] = fmaf(pk[k], inv, ATT_EPS);

    accS[0] += p0;
    accYbg[0] = fmaf(p0, xvb4.x, accYbg[0]);
    accYbg[1] = fmaf(p0, xvb4.y, accYbg[1]);
    accYbg[2] = fmaf(p0, xvb4.z, accYbg[2]);
    accYbg[3] = fmaf(p0, xvb4.w, accYbg[3]);
    if (LAST) accC[0] = fmaf(p0, fcv, accC[0]);
    #pragma unroll
    for (int k = 0; k < 4; ++k){
      accS[k+1] += pk[k];
      const float prv = pk[k]*rsv[k];
      accY[k][0] = fmaf(prv, cv4.x, accY[k][0]);
      accY[k][1] = fmaf(prv, cv4.y, accY[k][1]);
      accY[k][2] = fmaf(prv, cv4.z, accY[k][2]);
      accY[k][3] = fmaf(prv, cv4.w, accY[k][3]);
      accW0[k] += prv;
      accWx[k] = fmaf(prv, gx, accWx[k]);
      accWy[k] = fmaf(prv, gy, accWy[k]);
      if (LAST){
        accC[k+1] = fmaf(pk[k], fcv, accC[k+1]);
      } else {
        accP[k][0] = fmaf(pk[k], gx, accP[k][0]);
        accP[k][1] = fmaf(pk[k], gy, accP[k][1]);
        accT[k][0] = fmaf(pk[k], wpx, accT[k][0]);
        accT[k][1] = fmaf(pk[k], wpy, accT[k][1]);
      }
    }
  }

  #pragma unroll
  for (int k = 0; k < 4; ++k){
    #pragma unroll
    for (int j2 = 0; j2 < 4; ++j2){ float x = accY[k][j2]; XRED(x); accY[k][j2] = x; }
    float x;
    x = accW0[k]; XRED(x); accW0[k] = x;
    x = accWx[k]; XRED(x); accWx[k] = x;
    x = accWy[k]; XRED(x); accWy[k] = x;
    x = accP[k][0]; XRED(x); accP[k][0] = x;
    x = accP[k][1]; XRED(x); accP[k][1] = x;
    x = accT[k][0]; XRED(x); accT[k][0] = x;
    x = accT[k][1]; XRED(x); accT[k][1] = x;
  }
  #pragma unroll
  for (int j2 = 0; j2 < 4; ++j2){ float x = accYbg[j2]; XRED(x); accYbg[j2] = x; }
  #pragma unroll
  for (int sl = 0; sl < 5; ++sl){ float x = accS[sl]; XRED(x); accS[sl] = x; }
  #pragma unroll
  for (int sl = 0; sl < 5; ++sl){ float x = accC[sl]; XRED(x); accC[sl] = x; }

  const bool g0 = (G & 3) == 0;
  if (g0){
    #pragma unroll
    for (int k = 0; k < 4; ++k){
      atomicAdd(&red[A_Y + k*64 + e0 + 0], accY[k][0]);
      atomicAdd(&red[A_Y + k*64 + e0 + 1], accY[k][1]);
      atomicAdd(&red[A_Y + k*64 + e0 + 2], accY[k][2]);
      atomicAdd(&red[A_Y + k*64 + e0 + 3], accY[k][3]);
    }
    atomicAdd(&red[A_YBG + e0 + 0], accYbg[0]);
    atomicAdd(&red[A_YBG + e0 + 1], accYbg[1]);
    atomicAdd(&red[A_YBG + e0 + 2], accYbg[2]);
    atomicAdd(&red[A_YBG + e0 + 3], accYbg[3]);
    if (s == 0){
      #pragma unroll
      for (int sl = 0; sl < 5; ++sl) atomicAdd(&red[A_S + sl], accS[sl]);
      #pragma unroll
      for (int k = 0; k < 4; ++k){
        atomicAdd(&red[A_W0 + k], accW0[k]);
        atomicAdd(&red[A_WX + k], accWx[k]);
        atomicAdd(&red[A_WY + k], accWy[k]);
      }
      if (!LAST){
        #pragma unroll
        for (int k = 0; k < 4; ++k){
          atomicAdd(&red[A_P + k*2 + 0], accP[k][0]);
          atomicAdd(&red[A_P + k*2 + 1], accP[k][1]);
          atomicAdd(&red[A_T + k*2 + 0], accT[k][0]);
          atomicAdd(&red[A_T + k*2 + 1], accT[k][1]);
        }
      }
    }
    if (LAST && s < 8){
      #pragma unroll
      for (int sl = 0; sl < 5; ++sl) atomicAdd(&red[A_C + sl*8 + s], accC[sl]);
    }
  }
  __syncthreads();
  float* gacc = ws + OFF_ACC + ((size_t)b*2 + bank)*ACC_STRIDE;
  for (int i2 = tid; i2 < ACC_STRIDE; i2 += 256){
    const float v = red[i2];
    if (v != 0.0f) atomicAdd(&gacc[i2], v);
  }
}

// ---- merged slot update + next-iter prep. grid (5,16) x 64 ----
__global__ __launch_bounds__(64) void k_slotupd(
    const float* __restrict__ w_mlp_fg, const float* __restrict__ b_mlp_fg,
    const float* __restrict__ w_mlp_bg, const float* __restrict__ b_mlp_bg,
    const float* __restrict__ gfg_wih, const float* __restrict__ gfg_whh,
    const float* __restrict__ gfg_bih, const float* __restrict__ gfg_bhh,
    const float* __restrict__ gbg_wih, const float* __restrict__ gbg_whh,
    const float* __restrict__ gbg_bih, const float* __restrict__ gbg_bhh,
    const float* __restrict__ ln_rfg_g, const float* __restrict__ ln_rfg_b,
    const float* __restrict__ w_rfg, const float* __restrict__ b_rfg,
    const float* __restrict__ ln_rbg_g, const float* __restrict__ ln_rbg_b,
    const float* __restrict__ w_rbg, const float* __restrict__ b_rbg,
    const float* __restrict__ b_pos,
    const float* __restrict__ ln_fg_g, const float* __restrict__ ln_fg_b,
    const float* __restrict__ ln_q_g, const float* __restrict__ ln_q_b,
    const float* __restrict__ w_q,
    const float* __restrict__ ln_qbg_g, const float* __restrict__ ln_qbg_b,
    const float* __restrict__ w_qbg,
    const float* __restrict__ w_grid,
    float* __restrict__ ws, int rbank)
{
  const int k = blockIdx.x, b = blockIdx.y, d = threadIdx.x;
  float* accR = ws + OFF_ACC + ((size_t)b*2 + rbank)*ACC_STRIDE;
  float* accZ = ws + OFF_ACC + ((size_t)b*2 + (rbank^1))*ACC_STRIDE;
  __shared__ __align__(16) float xl[64], hl[64], rl[64];

  if (k < 4){
    const float wgx = w_grid[4*d] - w_grid[4*d+2];
    const float wgy = w_grid[4*d+1] - w_grid[4*d+3];
    const float mgx = wavesum(wgx)*(1.0f/64.0f);
    const float mgy = wavesum(wgy)*(1.0f/64.0f);
    const float cxg = (wgx - mgx)*ln_fg_g[d];
    const float cyg = (wgy - mgy)*ln_fg_g[d];
    const float invS = 1.0f/accR[A_S + 1 + k];
    const float pxv = ws[OFF_POS + b*8 + k*2 + 0];
    const float pyv = ws[OFF_POS + b*8 + k*2 + 1];
    const float wxc = (accR[A_WX + k] - pxv*accR[A_W0 + k])*invS;
    const float wyc = (accR[A_WY + k] - pyv*accR[A_W0 + k])*invS;
    xl[d] = accR[A_Y + k*64 + d]*invS*ln_fg_g[d] + wxc*cxg + wyc*cyg + ln_fg_b[d];
    const float h = ws[OFF_SFG + b*256 + k*64 + d];
    hl[d] = h;
    __syncthreads();
    const float upd = b_mlp_fg[d] + rowdot64f(w_mlp_fg + d*64, xl);
    __syncthreads();
    xl[d] = upd;
    __syncthreads();
    const float gir = gfg_bih[d]     + rowdot64f(gfg_wih + d*64, xl);
    const float giz = gfg_bih[64+d]  + rowdot64f(gfg_wih + (64+d)*64, xl);
    const float gin = gfg_bih[128+d] + rowdot64f(gfg_wih + (128+d)*64, xl);
    const float ghr = gfg_bhh[d]     + rowdot64f(gfg_whh + d*64, hl);
    const float ghz = gfg_bhh[64+d]  + rowdot64f(gfg_whh + (64+d)*64, hl);
    const float ghn = gfg_bhh[128+d] + rowdot64f(gfg_whh + (128+d)*64, hl);
    const float r = 1.0f/(1.0f + expf(-(gir+ghr)));
    const float z = 1.0f/(1.0f + expf(-(giz+ghz)));
    const float nng = tanhf(fmaf(r, ghn, gin));
    const float hnew = (1.0f - z)*nng + z*h;
    const float m = wavesum(hnew)*(1.0f/64.0f);
    const float c = hnew - m;
    const float var = wavesum(c*c)*(1.0f/64.0f);
    const float rs = rsqrtf(var + LNEPS);
    rl[d] = c*rs*ln_rfg_g[d] + ln_rfg_b[d];
    __syncthreads();
    const float snew = hnew + b_rfg[d] + rowdot64f(w_rfg + d*64, rl);
    ws[OFF_SFG + b*256 + k*64 + d] = snew;
    if (d < 2){
      const float P = accR[A_P + k*2 + d]*invS;
      const float T = accR[A_T + k*2 + d]*invS;
      float pn = P + tanhf(T + b_pos[d])*0.2f;
      pn = fminf(1.0f, fmaxf(-1.0f, pn));
      ws[OFF_POS + b*8 + k*2 + d] = pn;
    }
    // ---- prep next iter ----
    const float m2 = wavesum(snew)*(1.0f/64.0f);
    const float c2 = snew - m2;
    const float var2 = wavesum(c2*c2)*(1.0f/64.0f);
    const float rs2 = rsqrtf(var2 + LNEPS);
    xl[d] = c2*rs2*ln_q_g[d] + ln_q_b[d];
    __syncthreads();
    const float q = rowdot64f(w_q + d*64, xl);
    hl[d] = q;
    const float qb = wavesum(q * b_mlp_fg[d]);
    __syncthreads();
    const float qw = coldot64(w_mlp_fg, hl, d);
    ws[OFF_QW + b*256 + k*64 + d] = qw;
    const float A  = wavesum(qw * cxg);
    const float Bv = wavesum(qw * cyg);
    const float Cv = wavesum(qw * ln_fg_b[d]) + qb;
    if (d == 0){
      float* abc = ws + OFF_ABC + (size_t)(b*4 + k)*4;
      abc[0] = A; abc[1] = Bv; abc[2] = Cv;
    }
  } else {
    const float invS = 1.0f/accR[A_S];
    xl[d] = accR[A_YBG + d]*invS;
    const float h = ws[OFF_SBG + b*64 + d];
    hl[d] = h;
    __syncthreads();
    const float upd = b_mlp_bg[d] + rowdot64f(w_mlp_bg + d*64, xl);
    __syncthreads();
    xl[d] = upd;
    __syncthreads();
    const float gir = gbg_bih[d]     + rowdot64f(gbg_wih + d*64, xl);
    const float giz = gbg_bih[64+d]  + rowdot64f(gbg_wih + (64+d)*64, xl);
    const float gin = gbg_bih[128+d] + rowdot64f(gbg_wih + (128+d)*64, xl);
    const float ghr = gbg_bhh[d]     + rowdot64f(gbg_whh + d*64, hl);
    const float ghz = gbg_bhh[64+d]  + rowdot64f(gbg_whh + (64+d)*64, hl);
    const float ghn = gbg_bhh[128+d] + rowdot64f(gbg_whh + (128+d)*64, hl);
    const float r = 1.0f/(1.0f + expf(-(gir+ghr)));
    const float z = 1.0f/(1.0f + expf(-(giz+ghz)));
    const float nng = tanhf(fmaf(r, ghn, gin));
    const float hnew = (1.0f - z)*nng + z*h;
    const float m = wavesum(hnew)*(1.0f/64.0f);
    const float c = hnew - m;
    const float var = wavesum(c*c)*(1.0f/64.0f);
    const float rs = rsqrtf(var + LNEPS);
    rl[d] = c*rs*ln_rbg_g[d] + ln_rbg_b[d];
    __syncthreads();
    const float snew = hnew + b_rbg[d] + rowdot64f(w_rbg + d*64, rl);
    ws[OFF_SBG + b*64 + d] = snew;
    // ---- prep next iter (bg) ----
    const float m2 = wavesum(snew)*(1.0f/64.0f);
    const float c2 = snew - m2;
    const float var2 = wavesum(c2*c2)*(1.0f/64.0f);
    const float rs2 = rsqrtf(var2 + LNEPS);
    xl[d] = c2*rs2*ln_qbg_g[d] + ln_qbg_b[d];
    __syncthreads();
    const float q = rowdot64f(w_qbg + d*64, xl);
    hl[d] = q;
    const float qb = wavesum(q * b_mlp_bg[d]);
    __syncthreads();
    const float qw = coldot64(w_mlp_bg, hl, d);
    ws[OFF_QWBG + b*64 + d] = qw;
    if (d == 0) ws[OFF_QBBG + b] = qb;
    for (int i2 = d; i2 < ACC_STRIDE; i2 += 64) accZ[i2] = 0.0f;
  }
}

// ---- final output. grid (5,16) x 64, reads bank 1 ----
__global__ __launch_bounds__(64) void k_final(
    const float* __restrict__ w_mlp_fg, const float* __restrict__ b_mlp_fg,
    const float* __restrict__ w_mlp_bg, const float* __restrict__ b_mlp_bg,
    const float* __restrict__ ln_fg_g, const float* __restrict__ ln_fg_b,
    const float* __restrict__ w_grid,
    const float* __restrict__ ws, float* __restrict__ out)
{
  const int k = blockIdx.x, b = blockIdx.y, d = threadIdx.x;
  const float* acc = ws + OFF_ACC + ((size_t)b*2 + 1)*ACC_STRIDE;
  __shared__ __align__(16) float xl[64];
  if (k < 4){
    const float wgx = w_grid[4*d] - w_grid[4*d+2];
    const float wgy = w_grid[4*d+1] - w_grid[4*d+3];
    const float mgx = wavesum(wgx)*(1.0f/64.0f);
    const float mgy = wavesum(wgy)*(1.0f/64.0f);
    const float cxg = (wgx - mgx)*ln_fg_g[d];
    const float cyg = (wgy - mgy)*ln_fg_g[d];
    const float invS = 1.0f/acc[A_S + 1 + k];
    const float pxv = ws[OFF_POS + b*8 + k*2 + 0];
    const float pyv = ws[OFF_POS + b*8 + k*2 + 1];
    const float wxc = (acc[A_WX + k] - pxv*acc[A_W0 + k])*invS;
    const float wyc = (acc[A_WY + k] - pyv*acc[A_W0 + k])*invS;
    xl[d] = acc[A_Y + k*64 + d]*invS*ln_fg_g[d] + wxc*cxg + wyc*cyg + ln_fg_b[d];
    __syncthreads();
    const float o = b_mlp_fg[d] + rowdot64f(w_mlp_fg + d*64, xl);
    out[(size_t)(b*5 + 1 + k)*72 + d] = o;
    if (d < 8) out[(size_t)(b*5 + 1 + k)*72 + 64 + d] = acc[A_C + (k+1)*8 + d]*invS;
  } else {
    const float invS = 1.0f/acc[A_S];
    xl[d] = acc[A_YBG + d]*invS;
    __syncthreads();
    const float o = b_mlp_bg[d] + rowdot64f(w_mlp_bg + d*64, xl);
    out[(size_t)(b*5)*72 + d] = o;
    if (d < 8) out[(size_t)(b*5)*72 + 64 + d] = acc[A_C + d]*invS;
  }
}

extern "C" void kernel_launch(void* const* d_in, const int* in_sizes, int n_in,
                              void* d_out, int out_size, void* d_ws, size_t ws_size,
                              hipStream_t stream)
{
  const float* feat          = (const float*)d_in[0];
  const float* feat_color    = (const float*)d_in[1];
  const float* w_grid        = (const float*)d_in[2];
  const float* b_grid        = (const float*)d_in[3];
  const float* w_kfg         = (const float*)d_in[4];
  const float* w_vfg         = (const float*)d_in[5];
  const float* w_kbg         = (const float*)d_in[6];
  const float* w_vbg         = (const float*)d_in[7];
  const float* ln_fg_g       = (const float*)d_in[8];
  const float* ln_fg_b       = (const float*)d_in[9];
  const float* w_mlp_fg      = (const float*)d_in[10];
  const float* b_mlp_fg      = (const float*)d_in[11];
  const float* ln_bg_g       = (const float*)d_in[12];
  const float* ln_bg_b       = (const float*)d_in[13];
  const float* w_mlp_bg      = (const float*)d_in[14];
  const float* b_mlp_bg      = (const float*)d_in[15];
  const float* slots_init_fg = (const float*)d_in[16];
  const float* slots_init_bg = (const float*)d_in[17];
  const float* fg_position   = (const float*)d_in[18];
  const float* w_pos         = (const float*)d_in[19];
  const float* b_pos         = (const float*)d_in[20];
  const float* ln_q_g        = (const float*)d_in[21];
  const float* ln_q_b        = (const float*)d_in[22];
  const float* w_q           = (const float*)d_in[23];
  const float* ln_qbg_g      = (const float*)d_in[24];
  const float* ln_qbg_b      = (const float*)d_in[25];
  const float* w_qbg         = (const float*)d_in[26];
  const float* gfg_wih       = (const float*)d_in[27];
  const float* gfg_whh       = (const float*)d_in[28];
  const float* gfg_bih       = (const float*)d_in[29];
  const float* gfg_bhh       = (const float*)d_in[30];
  const float* gbg_wih       = (const float*)d_in[31];
  const float* gbg_whh       = (const float*)d_in[32];
  const float* gbg_bih       = (const float*)d_in[33];
  const float* gbg_bhh       = (const float*)d_in[34];
  const float* ln_rfg_g      = (const float*)d_in[35];
  const float* ln_rfg_b      = (const float*)d_in[36];
  const float* w_rfg         = (const float*)d_in[37];
  const float* b_rfg         = (const float*)d_in[38];
  const float* ln_rbg_g      = (const float*)d_in[39];
  const float* ln_rbg_b      = (const float*)d_in[40];
  const float* w_rbg         = (const float*)d_in[41];
  const float* b_rbg         = (const float*)d_in[42];
  const float* ln_feat_g     = (const float*)d_in[43];
  const float* ln_feat_b     = (const float*)d_in[44];
  const float* ln_fc_g       = (const float*)d_in[45];
  const float* ln_fc_b       = (const float*)d_in[46];
  float* ws  = (float*)d_ws;
  float* out = (float*)d_out;

  hipLaunchKernelGGL(k_init0, dim3(5,16), dim3(64), 0, stream,
                     slots_init_fg, slots_init_bg, fg_position, w_grid,
                     ln_fg_g, ln_fg_b, ln_q_g, ln_q_b, w_q,
                     ln_qbg_g, ln_qbg_b, w_qbg,
                     w_mlp_fg, b_mlp_fg, w_mlp_bg, b_mlp_bg, ws);
  hipLaunchKernelGGL(k_pre, dim3(1024), dim3(512), 0, stream,
                     feat, w_kfg, w_vfg, w_kbg, w_vbg, w_grid, b_grid,
                     ln_feat_g, ln_feat_b, ln_bg_g, ln_bg_b, ln_fg_g, ws);
  for (int it = 0; it < NITER; ++it){
    const int bank = it & 1;
    if (it < NITER-1){
      hipLaunchKernelGGL((k_main<0>), dim3(64,16), dim3(256), 0, stream,
                         feat_color, ln_fc_g, ln_fc_b, w_pos, ws, bank);
      hipLaunchKernelGGL(k_slotupd, dim3(5,16), dim3(64), 0, stream,
                         w_mlp_fg, b_mlp_fg, w_mlp_bg, b_mlp_bg,
                         gfg_wih, gfg_whh, gfg_bih, gfg_bhh,
                         gbg_wih, gbg_whh, gbg_bih, gbg_bhh,
                         ln_rfg_g, ln_rfg_b, w_rfg, b_rfg,
                         ln_rbg_g, ln_rbg_b, w_rbg, b_rbg,
                         b_pos, ln_fg_g, ln_fg_b,
                         ln_q_g, ln_q_b, w_q, ln_qbg_g, ln_qbg_b, w_qbg,
                         w_grid, ws, bank);
    } else {
      hipLaunchKernelGGL((k_main<1>), dim3(64,16), dim3(256), 0, stream,
                         feat_color, ln_fc_g, ln_fc_b, w_pos, ws, bank);
      hipLaunchKernelGGL(k_final, dim3(5,16), dim3(64), 0, stream,
                         w_mlp_fg, b_mlp_fg, w_mlp_bg, b_mlp_bg,
                         ln_fg_g, ln_fg_b, w_grid, ws, out);
    }
  }
}